// Round 9
// baseline (2574.054 us; speedup 1.0000x reference)
//
#include <hip/hip_runtime.h>

#define T_TOKENS 4096
#define DM 1024
#define DF 4096
#define KSEL 256
#define DH 64
#define DH2 32
#define BAND_DELTA 1.0e-2f
#define CAND_CAP (2 * 1024 * 1024)

typedef __attribute__((ext_vector_type(8))) short short8;
typedef __attribute__((ext_vector_type(4))) float f32x4;
typedef __attribute__((ext_vector_type(2))) float f32x2;

__device__ __forceinline__ f32x2 pkfma(f32x2 a, f32x2 b, f32x2 c) {
    return __builtin_elementwise_fma(a, b, c);
}

// exact-libm gelu: ONLY for the router path (scores must stay bitwise stable)
__device__ __forceinline__ float gelu_f(float x) {
    return 0.5f * x * (1.0f + erff(x * 0.70710678118654752440f));
}

// branch-free erf, Abramowitz-Stegun 7.1.26, |err| <= 1.5e-7 abs
__device__ __forceinline__ float erf_fast(float x) {
    float ax = __builtin_fabsf(x);
    float t = __builtin_amdgcn_rcpf(fmaf(0.3275911f, ax, 1.0f));
    float p = 1.061405429f;
    p = fmaf(p, t, -1.453152027f);
    p = fmaf(p, t, 1.421413741f);
    p = fmaf(p, t, -0.284496736f);
    p = fmaf(p, t, 0.254829592f);
    float e = __builtin_amdgcn_exp2f(-ax * ax * 1.44269504088896f);
    float r = fmaf(-p * t, e, 1.0f);
    return __builtin_copysignf(r, x);
}
__device__ __forceinline__ float gelu_fast(float x) {
    return 0.5f * x * (1.0f + erf_fast(x * 0.70710678118654752440f));
}

__device__ __forceinline__ unsigned short bf16_rne(float f) {
    unsigned u = __float_as_uint(f);
    unsigned r = (u + 0x7FFFu + ((u >> 16) & 1u)) >> 16;
    return (unsigned short)r;
}
__device__ __forceinline__ float bf16_to_f(unsigned short h) {
    return __uint_as_float(((unsigned)h) << 16);
}

// ---------------- LayerNorm over last dim (1024), one block per row ----------------
__global__ __launch_bounds__(256) void ln_kernel(const float* __restrict__ x,
                                                 const float* __restrict__ w,
                                                 const float* __restrict__ b,
                                                 float* __restrict__ out) {
    int row = blockIdx.x;
    int tid = threadIdx.x;
    const float4 v = ((const float4*)(x + (size_t)row * DM))[tid];
    float s = v.x + v.y + v.z + v.w;
    float s2 = v.x * v.x + v.y * v.y + v.z * v.z + v.w * v.w;
#pragma unroll
    for (int off = 32; off > 0; off >>= 1) {
        s += __shfl_xor(s, off);
        s2 += __shfl_xor(s2, off);
    }
    __shared__ float ss[4], ss2[4];
    int wave = tid >> 6;
    if ((tid & 63) == 0) { ss[wave] = s; ss2[wave] = s2; }
    __syncthreads();
    s = ss[0] + ss[1] + ss[2] + ss[3];
    s2 = ss2[0] + ss2[1] + ss2[2] + ss2[3];
    float mu = s * (1.0f / DM);
    float var = s2 * (1.0f / DM) - mu * mu;
    float rs = rsqrtf(var + 1e-5f);
    const float4 wv = ((const float4*)w)[tid];
    const float4 bv = ((const float4*)b)[tid];
    float4 o;
    o.x = (v.x - mu) * rs * wv.x + bv.x;
    o.y = (v.y - mu) * rs * wv.y + bv.y;
    o.z = (v.z - mu) * rs * wv.z + bv.z;
    o.w = (v.w - mu) * rs * wv.w + bv.w;
    ((float4*)(out + (size_t)row * DM))[tid] = o;
}

// ---------------- fp32 GEMM (router GEMM1 only): round-7 scalar version -----------
__global__ __launch_bounds__(256) void gemm_f32_128(const float* __restrict__ A,
                                                    const float* __restrict__ B,
                                                    float* __restrict__ C,
                                                    int M, int N, int K, int fuse_gelu) {
    __shared__ __align__(16) float As[16][132];
    __shared__ __align__(16) float Bs[16][132];
    int tid = threadIdx.x;
    int bm = blockIdx.y * 128, bn = blockIdx.x * 128;
    int tr = tid >> 4, tc = tid & 15;

    float4 avr[2], bvr[2];
    auto g_load = [&](int k0) {
#pragma unroll
        for (int s = 0; s < 2; s++) {
            int i = tid * 2 + s;
            int r = i >> 2, q = i & 3;
            avr[s] = *(const float4*)(A + (size_t)(bm + r) * K + k0 + q * 4);
            bvr[s] = *(const float4*)(B + (size_t)(bn + r) * K + k0 + q * 4);
        }
    };

    float acc[8][8] = {};
    g_load(0);
    for (int k0 = 0; k0 < K; k0 += 16) {
        __syncthreads();
#pragma unroll
        for (int s = 0; s < 2; s++) {
            int i = tid * 2 + s;
            int r = i >> 2, q = i & 3;
            As[q * 4 + 0][r] = avr[s].x; As[q * 4 + 1][r] = avr[s].y;
            As[q * 4 + 2][r] = avr[s].z; As[q * 4 + 3][r] = avr[s].w;
            Bs[q * 4 + 0][r] = bvr[s].x; Bs[q * 4 + 1][r] = bvr[s].y;
            Bs[q * 4 + 2][r] = bvr[s].z; Bs[q * 4 + 3][r] = bvr[s].w;
        }
        __syncthreads();
        if (k0 + 16 < K) g_load(k0 + 16);
#pragma unroll
        for (int kk = 0; kk < 16; kk++) {
            float4 a0 = *(const float4*)&As[kk][tr * 4];
            float4 a1 = *(const float4*)&As[kk][64 + tr * 4];
            float4 b0 = *(const float4*)&Bs[kk][tc * 4];
            float4 b1 = *(const float4*)&Bs[kk][64 + tc * 4];
            float ar[8] = {a0.x, a0.y, a0.z, a0.w, a1.x, a1.y, a1.z, a1.w};
            float br[8] = {b0.x, b0.y, b0.z, b0.w, b1.x, b1.y, b1.z, b1.w};
#pragma unroll
            for (int i = 0; i < 8; i++)
#pragma unroll
                for (int j = 0; j < 8; j++)
                    acc[i][j] = fmaf(ar[i], br[j], acc[i][j]);
        }
    }
#pragma unroll
    for (int i = 0; i < 8; i++) {
        int row = bm + (i < 4 ? tr * 4 + i : 64 + tr * 4 + (i - 4));
        float* cp = C + (size_t)row * N + bn;
        float4 o0, o1;
        if (fuse_gelu) {
            o0 = make_float4(gelu_f(acc[i][0]), gelu_f(acc[i][1]), gelu_f(acc[i][2]), gelu_f(acc[i][3]));
            o1 = make_float4(gelu_f(acc[i][4]), gelu_f(acc[i][5]), gelu_f(acc[i][6]), gelu_f(acc[i][7]));
        } else {
            o0 = make_float4(acc[i][0], acc[i][1], acc[i][2], acc[i][3]);
            o1 = make_float4(acc[i][4], acc[i][5], acc[i][6], acc[i][7]);
        }
        *(float4*)(cp + tc * 4) = o0;
        *(float4*)(cp + 64 + tc * 4) = o1;
    }
}

// ---------------- bf16 MFMA GEMM: C[M,N] (+)= A[M,K]*B[N,K]^T, strided rows -------
__global__ __launch_bounds__(256) void gemm_bf16(const short* __restrict__ A,
                                                 const short* __restrict__ B,
                                                 float* __restrict__ C,
                                                 int M, int N, int K,
                                                 int lda, int ldb, int beta) {
    __shared__ __align__(16) short As[128 * 64];
    __shared__ __align__(16) short Bs[128 * 64];
    int tid = threadIdx.x;
    int bm = blockIdx.y * 128, bn = blockIdx.x * 128;
    int lane = tid & 63, wave = tid >> 6;
    int wm = (wave >> 1) * 64, wn = (wave & 1) * 64;
    int quad = lane >> 4, l16 = lane & 15;
    int sr = tid >> 3, scp = tid & 7;

    short8 areg[4], breg[4];
    auto g_load = [&](int k0) {
#pragma unroll
        for (int j = 0; j < 4; j++) {
            int r = j * 32 + sr;
            int cl = scp ^ (r & 7);
            areg[j] = *(const short8*)(A + (size_t)(bm + r) * lda + k0 + cl * 8);
            breg[j] = *(const short8*)(B + (size_t)(bn + r) * ldb + k0 + cl * 8);
        }
    };

    f32x4 acc[4][4] = {};
    g_load(0);
    for (int k0 = 0; k0 < K; k0 += 64) {
        __syncthreads();
#pragma unroll
        for (int j = 0; j < 4; j++) {
            *(short8*)(As + (j * 256 + tid) * 8) = areg[j];
            *(short8*)(Bs + (j * 256 + tid) * 8) = breg[j];
        }
        __syncthreads();
        if (k0 + 64 < K) g_load(k0 + 64);
#pragma unroll
        for (int kk = 0; kk < 2; kk++) {
            short8 af[4], bf[4];
#pragma unroll
            for (int tm = 0; tm < 4; tm++) {
                int m = wm + tm * 16 + l16;
                int cp = (kk * 4 + quad) ^ (m & 7);
                af[tm] = *(const short8*)(As + m * 64 + cp * 8);
            }
#pragma unroll
            for (int tn = 0; tn < 4; tn++) {
                int n = wn + tn * 16 + l16;
                int cp = (kk * 4 + quad) ^ (n & 7);
                bf[tn] = *(const short8*)(Bs + n * 64 + cp * 8);
            }
#pragma unroll
            for (int tm = 0; tm < 4; tm++)
#pragma unroll
                for (int tn = 0; tn < 4; tn++)
                    acc[tm][tn] = __builtin_amdgcn_mfma_f32_16x16x32_bf16(
                        af[tm], bf[tn], acc[tm][tn], 0, 0, 0);
        }
    }
#pragma unroll
    for (int tm = 0; tm < 4; tm++)
#pragma unroll
        for (int tn = 0; tn < 4; tn++) {
            int row0 = bm + wm + tm * 16 + quad * 4;
            int col = bn + wn + tn * 16 + l16;
#pragma unroll
            for (int r = 0; r < 4; r++) {
                float* p = C + (size_t)(row0 + r) * N + col;
                float v = acc[tm][tn][r];
                if (beta) v += *p;
                *p = v;
            }
        }
}

// ---------------- fp32 -> concatenated (hi|lo) or (lo|hi) bf16 planes -------------
__global__ __launch_bounds__(256) void cvt_split_cat_kernel(const float* __restrict__ x,
                                                            short* __restrict__ cat,
                                                            int n4, int lo_first) {
    int i = blockIdx.x * 256 + threadIdx.x;
    if (i >= n4) return;
    float4 v = ((const float4*)x)[i];
    ushort4 h, l;
    h.x = bf16_rne(v.x); l.x = bf16_rne(v.x - bf16_to_f(h.x));
    h.y = bf16_rne(v.y); l.y = bf16_rne(v.y - bf16_to_f(h.y));
    h.z = bf16_rne(v.z); l.z = bf16_rne(v.z - bf16_to_f(h.z));
    h.w = bf16_rne(v.w); l.w = bf16_rne(v.w - bf16_to_f(h.w));
    int row = i >> 8;
    int col4 = i & 255;
    size_t base = (size_t)row * (2 * DM);
    size_t off_a = base + col4 * 4;
    size_t off_b = base + DM + col4 * 4;
    ((ushort4*)(cat + (lo_first ? off_b : off_a)))[0] = h;
    ((ushort4*)(cat + (lo_first ? off_a : off_b)))[0] = l;
}

__global__ __launch_bounds__(256) void cvt_bf16_kernel(const float* __restrict__ x,
                                                       short* __restrict__ y, int n4) {
    int i = blockIdx.x * 256 + threadIdx.x;
    if (i >= n4) return;
    float4 v = ((const float4*)x)[i];
    ushort4 h;
    h.x = bf16_rne(v.x); h.y = bf16_rne(v.y);
    h.z = bf16_rne(v.z); h.w = bf16_rne(v.w);
    ((ushort4*)y)[i] = h;
}

// ---------------- sortable-uint helpers -------------------------------------------
__device__ __forceinline__ unsigned sortable(float f) {
    unsigned u = __float_as_uint(f);
    return (u & 0x80000000u) ? ~u : (u | 0x80000000u);
}
__device__ __forceinline__ float unsortable(unsigned k) {
    unsigned b = (k & 0x80000000u) ? (k & 0x7FFFFFFFu) : ~k;
    return __uint_as_float(b);
}

// ---------------- radix kth-value + boundary-band collection ----------------------
// Finds each row's 256th-largest approx score, then appends (row<<12|col) for all
// cols with |score - kth| <= BAND_DELTA to a global candidate list.
__global__ __launch_bounds__(256) void topk_band_kernel(const float* __restrict__ scores,
                                                        int* __restrict__ cand,
                                                        int* __restrict__ gcount) {
    int row = blockIdx.x;
    int tid = threadIdx.x;
    __shared__ unsigned s_keys[DF];
    __shared__ int hist[256];
    __shared__ int sufs[256];
    __shared__ int s_misc[4];

    const float* sr = scores + (size_t)row * DF;
    for (int i = tid; i < DF; i += 256) s_keys[i] = sortable(sr[i]);

    unsigned prefix = 0;
    int krem = KSEL;
    for (int pass = 0; pass < 4; pass++) {
        int shift = 24 - pass * 8;
        unsigned hmask = (pass == 0) ? 0u : (0xFFFFFFFFu << (shift + 8));
        hist[tid] = 0;
        __syncthreads();
        for (int i = tid; i < DF; i += 256) {
            unsigned u = s_keys[i];
            if ((u & hmask) == prefix) atomicAdd(&hist[(u >> shift) & 0xFF], 1);
        }
        __syncthreads();
        sufs[tid] = hist[tid];
        __syncthreads();
#pragma unroll
        for (int off = 1; off < 256; off <<= 1) {
            int add = (tid + off < 256) ? sufs[tid + off] : 0;
            __syncthreads();
            sufs[tid] += add;
            __syncthreads();
        }
        if (sufs[tid] >= krem && (tid == 255 || sufs[tid + 1] < krem)) {
            s_misc[0] = tid;
            s_misc[1] = sufs[tid] - hist[tid];
        }
        __syncthreads();
        prefix |= ((unsigned)s_misc[0]) << shift;
        krem -= s_misc[1];
        __syncthreads();
    }
    float vf = unsortable(prefix);
    for (int i = tid; i < DF; i += 256) {
        float d = sr[i] - vf;
        if (__builtin_fabsf(d) <= BAND_DELTA) {
            int p = atomicAdd(gcount, 1);
            if (p < CAND_CAP) cand[p] = (row << 12) | i;
        }
    }
}

// ---------------- exact fp32 re-score of band candidates --------------------------
// One wave per candidate; 64 lanes split the K=1024 dot (coalesced float4 loads).
__global__ __launch_bounds__(256) void rescore_kernel(const float* __restrict__ h,
                                                      const float* __restrict__ Wr2,
                                                      const int* __restrict__ cand,
                                                      const int* __restrict__ gcount,
                                                      float* __restrict__ scores) {
    int lane = threadIdx.x & 63;
    int wave_id = blockIdx.x * 4 + (threadIdx.x >> 6);
    int n_waves = gridDim.x * 4;
    int count = *gcount;
    if (count > CAND_CAP) count = CAND_CAP;
    for (int c = wave_id; c < count; c += n_waves) {
        int rc = cand[c];
        int row = rc >> 12, col = rc & 0xFFF;
        const float4* hp = (const float4*)(h + (size_t)row * DM);
        const float4* wp = (const float4*)(Wr2 + (size_t)col * DM);
        float s = 0.f;
#pragma unroll
        for (int j = 0; j < 4; j++) {
            float4 a = hp[lane + 64 * j];
            float4 b = wp[lane + 64 * j];
            s = fmaf(a.x, b.x, s);
            s = fmaf(a.y, b.y, s);
            s = fmaf(a.z, b.z, s);
            s = fmaf(a.w, b.w, s);
        }
#pragma unroll
        for (int st = 1; st < 64; st <<= 1) s += __shfl_xor(s, st);
        if (lane == 0) scores[(size_t)row * DF + col] = s;
    }
}

// ---------------- top-k (k=256 of 4096) per row, exact tie-break ------------------
__global__ __launch_bounds__(256) void topk_kernel(const float* __restrict__ scores,
                                                   int* __restrict__ top_idx) {
    int row = blockIdx.x;
    int tid = threadIdx.x;
    __shared__ unsigned s_keys[DF];
    __shared__ int hist[256];
    __shared__ int sufs[256];
    __shared__ int s_misc[4];
    __shared__ int s_wsums[4];

    const float* sr = scores + (size_t)row * DF;
    for (int i = tid; i < DF; i += 256) s_keys[i] = sortable(sr[i]);

    unsigned prefix = 0;
    int krem = KSEL;
    for (int pass = 0; pass < 4; pass++) {
        int shift = 24 - pass * 8;
        unsigned hmask = (pass == 0) ? 0u : (0xFFFFFFFFu << (shift + 8));
        hist[tid] = 0;
        __syncthreads();
        for (int i = tid; i < DF; i += 256) {
            unsigned u = s_keys[i];
            if ((u & hmask) == prefix) atomicAdd(&hist[(u >> shift) & 0xFF], 1);
        }
        __syncthreads();
        sufs[tid] = hist[tid];
        __syncthreads();
#pragma unroll
        for (int off = 1; off < 256; off <<= 1) {
            int add = (tid + off < 256) ? sufs[tid + off] : 0;
            __syncthreads();
            sufs[tid] += add;
            __syncthreads();
        }
        if (sufs[tid] >= krem && (tid == 255 || sufs[tid + 1] < krem)) {
            s_misc[0] = tid;
            s_misc[1] = sufs[tid] - hist[tid];
        }
        __syncthreads();
        prefix |= ((unsigned)s_misc[0]) << shift;
        krem -= s_misc[1];
        __syncthreads();
    }
    unsigned v = prefix;
    if (tid == 0) s_misc[2] = 0;
    __syncthreads();
    int* out = top_idx + (size_t)row * KSEL;
    for (int i = tid; i < DF; i += 256) {
        if (s_keys[i] > v) {
            int p = atomicAdd(&s_misc[2], 1);
            out[p] = i;
        }
    }
    __syncthreads();
    int base = s_misc[2];
    int lane = tid & 63, wave = tid >> 6;
    int taken = 0;
    for (int chunk = 0; chunk < DF / 256; chunk++) {
        int i = chunk * 256 + tid;
        int flag = (s_keys[i] == v) ? 1 : 0;
        unsigned long long mb = __ballot(flag);
        int before = __popcll(mb & ((1ULL << lane) - 1ULL));
        if (lane == 0) s_wsums[wave] = __popcll(mb);
        __syncthreads();
        int woff = 0;
#pragma unroll
        for (int w = 0; w < 4; w++) if (w < wave) woff += s_wsums[w];
        int total = s_wsums[0] + s_wsums[1] + s_wsums[2] + s_wsums[3];
        int excl = woff + before;
        if (flag && (taken + excl) < krem) out[base + taken + excl] = i;
        taken += total;
        __syncthreads();
    }
}

// ---------------- DeepSets manifold: one block per token, one k per thread --------
__global__ __launch_bounds__(256) void manifold_kernel(
    const float* __restrict__ z, const int* __restrict__ top_idx,
    const float* __restrict__ phi1_w, const float* __restrict__ phi1_b,
    const float* __restrict__ ln1w, const float* __restrict__ ln1b,
    const float* __restrict__ phi2_w, const float* __restrict__ phi2_b,
    const float* __restrict__ ln2w, const float* __restrict__ ln2b,
    const float* __restrict__ rho1_w, const float* __restrict__ rho1_b,
    const float* __restrict__ rho2_w, const float* __restrict__ rho2_b,
    float* __restrict__ man) {
    __shared__ float s_ctxp[4 * DH];
    __shared__ float s_ctx[DH];

    int tid = threadIdx.x;
    int t = blockIdx.x;
    int lane = tid & 63, wave = tid >> 6;

    int idx = top_idx[(size_t)t * KSEL + tid];
    float a = gelu_fast(z[(size_t)t * DF + idx]);
    f32x2 a2 = {a, a};

    f32x2 gv[DH2 / 2];
    f32x2 sv = {0.f, 0.f}, qv = {0.f, 0.f};
#pragma unroll
    for (int i = 0; i < DH2 / 2; i++) {
        f32x2 w = ((const f32x2*)phi1_w)[i];
        f32x2 b = ((const f32x2*)phi1_b)[i];
        f32x2 e = pkfma(a2, w, b);
        gv[i] = e;
        sv = sv + e;
        qv = pkfma(e, e, qv);
    }
    float s = sv.x + sv.y, s2 = qv.x + qv.y;
    float mu = s * (1.0f / DH2);
    float rs = rsqrtf(s2 * (1.0f / DH2) - mu * mu + 1e-5f);
    f32x2 muv = {mu, mu}, rsv = {rs, rs};
#pragma unroll
    for (int i = 0; i < DH2 / 2; i++) {
        f32x2 t2 = (gv[i] - muv) * rsv;
        t2 = pkfma(t2, ((const f32x2*)ln1w)[i], ((const f32x2*)ln1b)[i]);
        gv[i] = (f32x2){gelu_fast(t2.x), gelu_fast(t2.y)};
    }

    f32x2 hv[DH / 2];
#pragma unroll
    for (int j2 = 0; j2 < DH / 2; j2++) {
        const f32x2* wa = (const f32x2*)(phi2_w + (2 * j2) * DH2);
        const f32x2* wb = (const f32x2*)(phi2_w + (2 * j2 + 1) * DH2);
        f32x2 ra = {phi2_b[2 * j2], 0.f};
        f32x2 rb = {phi2_b[2 * j2 + 1], 0.f};
#pragma unroll
        for (int i = 0; i < DH2 / 2; i++) {
            ra = pkfma(gv[i], wa[i], ra);
            rb = pkfma(gv[i], wb[i], rb);
        }
        hv[j2] = (f32x2){ra.x + ra.y, rb.x + rb.y};
    }

    f32x2 tsv = {0.f, 0.f}, tqv = {0.f, 0.f};
#pragma unroll
    for (int j2 = 0; j2 < DH / 2; j2++) {
        tsv = tsv + hv[j2];
        tqv = pkfma(hv[j2], hv[j2], tqv);
    }
    float tsum = tsv.x + tsv.y, tsq = tqv.x + tqv.y;
    float mu2 = tsum * (1.0f / DH);
    float rs2 = rsqrtf(tsq * (1.0f / DH) - mu2 * mu2 + 1e-5f);
    f32x2 mu2v = {mu2, mu2}, rs2v = {rs2, rs2};
#pragma unroll
    for (int j2 = 0; j2 < DH / 2; j2++) {
        f32x2 t2 = (hv[j2] - mu2v) * rs2v;
        hv[j2] = pkfma(t2, ((const f32x2*)ln2w)[j2], ((const f32x2*)ln2b)[j2]);
    }

#pragma unroll
    for (int j2 = 0; j2 < DH / 2; j2++) {
        float vx = hv[j2].x, vy = hv[j2].y;
#pragma unroll
        for (int st = 1; st < 64; st <<= 1) {
            vx += __shfl_xor(vx, st);
            vy += __shfl_xor(vy, st);
        }
        if (lane == 0) {
            s_ctxp[wave * DH + 2 * j2] = vx;
            s_ctxp[wave * DH + 2 * j2 + 1] = vy;
        }
    }
    __syncthreads();
    if (tid < DH)
        s_ctx[tid] = (s_ctxp[tid] + s_ctxp[DH + tid] + s_ctxp[2 * DH + tid] +
                      s_ctxp[3 * DH + tid]) * (1.0f / KSEL);
    __syncthreads();

#pragma unroll
    for (int j2 = 0; j2 < DH / 2; j2++) hv[j2] = hv[j2] + ((const f32x2*)s_ctx)[j2];
    float m = rho2_b[0];
    for (int p = 0; p < 2 * DH; p++) {
        const f32x2* wp = (const f32x2*)(rho1_w + p * DH);
        f32x2 r0 = {rho1_b[p], 0.f};
        f32x2 r1 = {0.f, 0.f};
#pragma unroll
        for (int q2 = 0; q2 < DH / 2; q2 += 2) {
            r0 = pkfma(hv[q2], wp[q2], r0);
            r1 = pkfma(hv[q2 + 1], wp[q2 + 1], r1);
        }
        float r = (r0.x + r0.y) + (r1.x + r1.y);
        m = fmaf(gelu_fast(r), rho2_w[p], m);
    }
    man[(size_t)t * KSEL + tid] = m;
}

// ---------------- scatter man (as bf16) into zeroed bf16 a_man --------------------
__global__ __launch_bounds__(256) void scatter_bf16_kernel(const float* __restrict__ man,
                                                           const int* __restrict__ top_idx,
                                                           short* __restrict__ a_man) {
    int t = blockIdx.x, k = threadIdx.x;
    a_man[(size_t)t * DF + top_idx[(size_t)t * KSEL + k]] =
        (short)bf16_rne(man[(size_t)t * KSEL + k]);
}

extern "C" void kernel_launch(void* const* d_in, const int* in_sizes, int n_in,
                              void* d_out, int out_size, void* d_ws, size_t ws_size,
                              hipStream_t stream) {
    const float* x      = (const float*)d_in[0];
    const float* W1     = (const float*)d_in[1];
    const float* W2     = (const float*)d_in[2];
    const float* Wr1    = (const float*)d_in[3];
    const float* Wr2    = (const float*)d_in[4];
    const float* ln_w   = (const float*)d_in[5];
    const float* ln_b   = (const float*)d_in[6];
    const float* phi1_w = (const float*)d_in[7];
    const float* phi1_b = (const float*)d_in[8];
    const float* pl1w   = (const float*)d_in[9];
    const float* pl1b   = (const float*)d_in[10];
    const float* phi2_w = (const float*)d_in[11];
    const float* phi2_b = (const float*)d_in[12];
    const float* pl2w   = (const float*)d_in[13];
    const float* pl2b   = (const float*)d_in[14];
    const float* rho1_w = (const float*)d_in[15];
    const float* rho1_b = (const float*)d_in[16];
    const float* rho2_w = (const float*)d_in[17];
    const float* rho2_b = (const float*)d_in[18];
    float* out = (float*)d_out;

    char* ws = (char*)d_ws;
    size_t off = 0;
    auto alloc = [&](size_t bytes) {
        char* p = ws + off;
        off += (bytes + 255) & ~(size_t)255;
        return p;
    };
    float* xn     = (float*)alloc(sizeof(float) * (size_t)T_TOKENS * DM);   // 16 MB
    float* h      = (float*)alloc(sizeof(float) * (size_t)T_TOKENS * DM);   // 16 MB
    float* scores = (float*)alloc(sizeof(float) * (size_t)T_TOKENS * DF);   // 64 MB
    float* z      = (float*)alloc(sizeof(float) * (size_t)T_TOKENS * DF);   // 64 MB
    int*   tidx   = (int*)alloc(sizeof(int) * (size_t)T_TOKENS * KSEL);     // 4 MB
    float* man    = (float*)alloc(sizeof(float) * (size_t)T_TOKENS * KSEL); // 4 MB
    int*   cand   = (int*)alloc(sizeof(int) * (size_t)CAND_CAP);            // 8 MB
    int*   gcount = (int*)alloc(256);

    // Region reuse (stream-serial, lifetimes disjoint):
    short* h_hi   = (short*)z;                      // 8 MB (z unused until step 6)
    short* wr2_hi = (short*)z + (size_t)T_TOKENS * DM;  // next 8 MB of z
    short* xcat  = (short*)xn;      // [4096 x 2048]: [xh | xl], after router
    short* w1cat = (short*)h;       // [4096 x 2048]: [w1l | w1h], after rescore
    short* amanb = (short*)scores;  // 32 MB, after topk2
    short* w2b   = (short*)z;       // 8 MB, after manifold

    // 1. x_norm = LN(x)
    ln_kernel<<<T_TOKENS, 256, 0, stream>>>(x, ln_w, ln_b, xn);
    // 2. h = gelu(xn @ Wr1^T)   (fp32 exact — h feeds exact rescoring)
    gemm_f32_128<<<dim3(DM / 128, T_TOKENS / 128), 256, 0, stream>>>(xn, Wr1, h, T_TOKENS, DM, DM, 1);
    // 3. approx scores = h_hi @ Wr2_hi^T  (bf16 MFMA)
    cvt_bf16_kernel<<<(T_TOKENS * DM / 4 + 255) / 256, 256, 0, stream>>>(h, h_hi, T_TOKENS * DM / 4);
    cvt_bf16_kernel<<<(DF * DM / 4 + 255) / 256, 256, 0, stream>>>(Wr2, wr2_hi, DF * DM / 4);
    gemm_bf16<<<dim3(DF / 128, T_TOKENS / 128), 256, 0, stream>>>(
        h_hi, wr2_hi, scores, T_TOKENS, DF, DM, DM, DM, 0);
    // 4. find per-row 256th value + collect boundary band
    hipMemsetAsync(gcount, 0, sizeof(int), stream);
    topk_band_kernel<<<T_TOKENS, 256, 0, stream>>>(scores, cand, gcount);
    // 5. exact fp32 re-score of band candidates, then final top-k
    rescore_kernel<<<2048, 256, 0, stream>>>(h, Wr2, cand, gcount, scores);
    topk_kernel<<<T_TOKENS, 256, 0, stream>>>(scores, tidx);
    // 6. split x -> [xh|xl], W1 -> [w1l|w1h]
    cvt_split_cat_kernel<<<(T_TOKENS * DM / 4 + 255) / 256, 256, 0, stream>>>(x, xcat, T_TOKENS * DM / 4, 0);
    cvt_split_cat_kernel<<<(DF * DM / 4 + 255) / 256, 256, 0, stream>>>(W1, w1cat, DF * DM / 4, 1);
    // 7. z = x @ W1^T: hi*hi (K=1024) + merged cross terms (K=2048)
    gemm_bf16<<<dim3(DF / 128, T_TOKENS / 128), 256, 0, stream>>>(
        xcat, w1cat + DM, z, T_TOKENS, DF, DM, 2 * DM, 2 * DM, 0);
    gemm_bf16<<<dim3(DF / 128, T_TOKENS / 128), 256, 0, stream>>>(
        xcat, w1cat, z, T_TOKENS, DF, 2 * DM, 2 * DM, 2 * DM, 1);
    // 8. manifold
    manifold_kernel<<<T_TOKENS, 256, 0, stream>>>(z, tidx, phi1_w, phi1_b, pl1w, pl1b,
                                                  phi2_w, phi2_b, pl2w, pl2b,
                                                  rho1_w, rho1_b, rho2_w, rho2_b, man);
    // 9. scatter man -> bf16 a_man; W2 -> bf16
    hipMemsetAsync(amanb, 0, sizeof(short) * (size_t)T_TOKENS * DF, stream);
    scatter_bf16_kernel<<<T_TOKENS, 256, 0, stream>>>(man, tidx, amanb);
    cvt_bf16_kernel<<<(DM * DF / 4 + 255) / 256, 256, 0, stream>>>(W2, w2b, DM * DF / 4);
    // 10. out = a_man @ W2^T  (plain bf16 MFMA)
    gemm_bf16<<<dim3(DM / 128, T_TOKENS / 128), 256, 0, stream>>>(
        amanb, w2b, out, T_TOKENS, DM, DF, DF, DF, 0);
}

// Round 10
// 1044.105 us; speedup vs baseline: 2.4653x; 2.4653x over previous
//
#include <hip/hip_runtime.h>

#define T_TOKENS 4096
#define DM 1024
#define DF 4096
#define KSEL 256
#define DH 64
#define DH2 32
#define BAND_DELTA 1.0e-2f
#define CAP_ROW 256

typedef __attribute__((ext_vector_type(8))) short short8;
typedef __attribute__((ext_vector_type(4))) float f32x4;
typedef __attribute__((ext_vector_type(2))) float f32x2;

__device__ __forceinline__ f32x2 pkfma(f32x2 a, f32x2 b, f32x2 c) {
    return __builtin_elementwise_fma(a, b, c);
}

// exact-libm gelu: ONLY for the router path
__device__ __forceinline__ float gelu_f(float x) {
    return 0.5f * x * (1.0f + erff(x * 0.70710678118654752440f));
}

// branch-free erf, Abramowitz-Stegun 7.1.26, |err| <= 1.5e-7 abs
__device__ __forceinline__ float erf_fast(float x) {
    float ax = __builtin_fabsf(x);
    float t = __builtin_amdgcn_rcpf(fmaf(0.3275911f, ax, 1.0f));
    float p = 1.061405429f;
    p = fmaf(p, t, -1.453152027f);
    p = fmaf(p, t, 1.421413741f);
    p = fmaf(p, t, -0.284496736f);
    p = fmaf(p, t, 0.254829592f);
    float e = __builtin_amdgcn_exp2f(-ax * ax * 1.44269504088896f);
    float r = fmaf(-p * t, e, 1.0f);
    return __builtin_copysignf(r, x);
}
__device__ __forceinline__ float gelu_fast(float x) {
    return 0.5f * x * (1.0f + erf_fast(x * 0.70710678118654752440f));
}

__device__ __forceinline__ unsigned short bf16_rne(float f) {
    unsigned u = __float_as_uint(f);
    unsigned r = (u + 0x7FFFu + ((u >> 16) & 1u)) >> 16;
    return (unsigned short)r;
}
__device__ __forceinline__ float bf16_to_f(unsigned short h) {
    return __uint_as_float(((unsigned)h) << 16);
}

// ---------------- LayerNorm over last dim (1024), one block per row ----------------
__global__ __launch_bounds__(256) void ln_kernel(const float* __restrict__ x,
                                                 const float* __restrict__ w,
                                                 const float* __restrict__ b,
                                                 float* __restrict__ out) {
    int row = blockIdx.x;
    int tid = threadIdx.x;
    const float4 v = ((const float4*)(x + (size_t)row * DM))[tid];
    float s = v.x + v.y + v.z + v.w;
    float s2 = v.x * v.x + v.y * v.y + v.z * v.z + v.w * v.w;
#pragma unroll
    for (int off = 32; off > 0; off >>= 1) {
        s += __shfl_xor(s, off);
        s2 += __shfl_xor(s2, off);
    }
    __shared__ float ss[4], ss2[4];
    int wave = tid >> 6;
    if ((tid & 63) == 0) { ss[wave] = s; ss2[wave] = s2; }
    __syncthreads();
    s = ss[0] + ss[1] + ss[2] + ss[3];
    s2 = ss2[0] + ss2[1] + ss2[2] + ss2[3];
    float mu = s * (1.0f / DM);
    float var = s2 * (1.0f / DM) - mu * mu;
    float rs = rsqrtf(var + 1e-5f);
    const float4 wv = ((const float4*)w)[tid];
    const float4 bv = ((const float4*)b)[tid];
    float4 o;
    o.x = (v.x - mu) * rs * wv.x + bv.x;
    o.y = (v.y - mu) * rs * wv.y + bv.y;
    o.z = (v.z - mu) * rs * wv.z + bv.z;
    o.w = (v.w - mu) * rs * wv.w + bv.w;
    ((float4*)(out + (size_t)row * DM))[tid] = o;
}

// ---------------- fp32 GEMM (router GEMM1 only) ------------------------------------
__global__ __launch_bounds__(256) void gemm_f32_128(const float* __restrict__ A,
                                                    const float* __restrict__ B,
                                                    float* __restrict__ C,
                                                    int M, int N, int K, int fuse_gelu) {
    __shared__ __align__(16) float As[16][132];
    __shared__ __align__(16) float Bs[16][132];
    int tid = threadIdx.x;
    int bm = blockIdx.y * 128, bn = blockIdx.x * 128;
    int tr = tid >> 4, tc = tid & 15;

    float4 avr[2], bvr[2];
    auto g_load = [&](int k0) {
#pragma unroll
        for (int s = 0; s < 2; s++) {
            int i = tid * 2 + s;
            int r = i >> 2, q = i & 3;
            avr[s] = *(const float4*)(A + (size_t)(bm + r) * K + k0 + q * 4);
            bvr[s] = *(const float4*)(B + (size_t)(bn + r) * K + k0 + q * 4);
        }
    };

    float acc[8][8] = {};
    g_load(0);
    for (int k0 = 0; k0 < K; k0 += 16) {
        __syncthreads();
#pragma unroll
        for (int s = 0; s < 2; s++) {
            int i = tid * 2 + s;
            int r = i >> 2, q = i & 3;
            As[q * 4 + 0][r] = avr[s].x; As[q * 4 + 1][r] = avr[s].y;
            As[q * 4 + 2][r] = avr[s].z; As[q * 4 + 3][r] = avr[s].w;
            Bs[q * 4 + 0][r] = bvr[s].x; Bs[q * 4 + 1][r] = bvr[s].y;
            Bs[q * 4 + 2][r] = bvr[s].z; Bs[q * 4 + 3][r] = bvr[s].w;
        }
        __syncthreads();
        if (k0 + 16 < K) g_load(k0 + 16);
#pragma unroll
        for (int kk = 0; kk < 16; kk++) {
            float4 a0 = *(const float4*)&As[kk][tr * 4];
            float4 a1 = *(const float4*)&As[kk][64 + tr * 4];
            float4 b0 = *(const float4*)&Bs[kk][tc * 4];
            float4 b1 = *(const float4*)&Bs[kk][64 + tc * 4];
            float ar[8] = {a0.x, a0.y, a0.z, a0.w, a1.x, a1.y, a1.z, a1.w};
            float br[8] = {b0.x, b0.y, b0.z, b0.w, b1.x, b1.y, b1.z, b1.w};
#pragma unroll
            for (int i = 0; i < 8; i++)
#pragma unroll
                for (int j = 0; j < 8; j++)
                    acc[i][j] = fmaf(ar[i], br[j], acc[i][j]);
        }
    }
#pragma unroll
    for (int i = 0; i < 8; i++) {
        int row = bm + (i < 4 ? tr * 4 + i : 64 + tr * 4 + (i - 4));
        float* cp = C + (size_t)row * N + bn;
        float4 o0, o1;
        if (fuse_gelu) {
            o0 = make_float4(gelu_f(acc[i][0]), gelu_f(acc[i][1]), gelu_f(acc[i][2]), gelu_f(acc[i][3]));
            o1 = make_float4(gelu_f(acc[i][4]), gelu_f(acc[i][5]), gelu_f(acc[i][6]), gelu_f(acc[i][7]));
        } else {
            o0 = make_float4(acc[i][0], acc[i][1], acc[i][2], acc[i][3]);
            o1 = make_float4(acc[i][4], acc[i][5], acc[i][6], acc[i][7]);
        }
        *(float4*)(cp + tc * 4) = o0;
        *(float4*)(cp + 64 + tc * 4) = o1;
    }
}

// ---------------- bf16 MFMA GEMM: C[M,N] (+)= A[M,K]*B[N,K]^T, strided rows -------
__global__ __launch_bounds__(256) void gemm_bf16(const short* __restrict__ A,
                                                 const short* __restrict__ B,
                                                 float* __restrict__ C,
                                                 int M, int N, int K,
                                                 int lda, int ldb, int beta) {
    __shared__ __align__(16) short As[128 * 64];
    __shared__ __align__(16) short Bs[128 * 64];
    int tid = threadIdx.x;
    int bm = blockIdx.y * 128, bn = blockIdx.x * 128;
    int lane = tid & 63, wave = tid >> 6;
    int wm = (wave >> 1) * 64, wn = (wave & 1) * 64;
    int quad = lane >> 4, l16 = lane & 15;
    int sr = tid >> 3, scp = tid & 7;

    short8 areg[4], breg[4];
    auto g_load = [&](int k0) {
#pragma unroll
        for (int j = 0; j < 4; j++) {
            int r = j * 32 + sr;
            int cl = scp ^ (r & 7);
            areg[j] = *(const short8*)(A + (size_t)(bm + r) * lda + k0 + cl * 8);
            breg[j] = *(const short8*)(B + (size_t)(bn + r) * ldb + k0 + cl * 8);
        }
    };

    f32x4 acc[4][4] = {};
    g_load(0);
    for (int k0 = 0; k0 < K; k0 += 64) {
        __syncthreads();
#pragma unroll
        for (int j = 0; j < 4; j++) {
            *(short8*)(As + (j * 256 + tid) * 8) = areg[j];
            *(short8*)(Bs + (j * 256 + tid) * 8) = breg[j];
        }
        __syncthreads();
        if (k0 + 64 < K) g_load(k0 + 64);
#pragma unroll
        for (int kk = 0; kk < 2; kk++) {
            short8 af[4], bf[4];
#pragma unroll
            for (int tm = 0; tm < 4; tm++) {
                int m = wm + tm * 16 + l16;
                int cp = (kk * 4 + quad) ^ (m & 7);
                af[tm] = *(const short8*)(As + m * 64 + cp * 8);
            }
#pragma unroll
            for (int tn = 0; tn < 4; tn++) {
                int n = wn + tn * 16 + l16;
                int cp = (kk * 4 + quad) ^ (n & 7);
                bf[tn] = *(const short8*)(Bs + n * 64 + cp * 8);
            }
#pragma unroll
            for (int tm = 0; tm < 4; tm++)
#pragma unroll
                for (int tn = 0; tn < 4; tn++)
                    acc[tm][tn] = __builtin_amdgcn_mfma_f32_16x16x32_bf16(
                        af[tm], bf[tn], acc[tm][tn], 0, 0, 0);
        }
    }
#pragma unroll
    for (int tm = 0; tm < 4; tm++)
#pragma unroll
        for (int tn = 0; tn < 4; tn++) {
            int row0 = bm + wm + tm * 16 + quad * 4;
            int col = bn + wn + tn * 16 + l16;
#pragma unroll
            for (int r = 0; r < 4; r++) {
                float* p = C + (size_t)(row0 + r) * N + col;
                float v = acc[tm][tn][r];
                if (beta) v += *p;
                *p = v;
            }
        }
}

// ---------------- fp32 -> concatenated (hi|lo) or (lo|hi) bf16 planes -------------
__global__ __launch_bounds__(256) void cvt_split_cat_kernel(const float* __restrict__ x,
                                                            short* __restrict__ cat,
                                                            int n4, int lo_first) {
    int i = blockIdx.x * 256 + threadIdx.x;
    if (i >= n4) return;
    float4 v = ((const float4*)x)[i];
    ushort4 h, l;
    h.x = bf16_rne(v.x); l.x = bf16_rne(v.x - bf16_to_f(h.x));
    h.y = bf16_rne(v.y); l.y = bf16_rne(v.y - bf16_to_f(h.y));
    h.z = bf16_rne(v.z); l.z = bf16_rne(v.z - bf16_to_f(h.z));
    h.w = bf16_rne(v.w); l.w = bf16_rne(v.w - bf16_to_f(h.w));
    int row = i >> 8;
    int col4 = i & 255;
    size_t base = (size_t)row * (2 * DM);
    size_t off_a = base + col4 * 4;
    size_t off_b = base + DM + col4 * 4;
    ((ushort4*)(cat + (lo_first ? off_b : off_a)))[0] = h;
    ((ushort4*)(cat + (lo_first ? off_a : off_b)))[0] = l;
}

__global__ __launch_bounds__(256) void cvt_bf16_kernel(const float* __restrict__ x,
                                                       short* __restrict__ y, int n4) {
    int i = blockIdx.x * 256 + threadIdx.x;
    if (i >= n4) return;
    float4 v = ((const float4*)x)[i];
    ushort4 h;
    h.x = bf16_rne(v.x); h.y = bf16_rne(v.y);
    h.z = bf16_rne(v.z); h.w = bf16_rne(v.w);
    ((ushort4*)y)[i] = h;
}

// ---------------- sortable-uint helpers -------------------------------------------
__device__ __forceinline__ unsigned sortable(float f) {
    unsigned u = __float_as_uint(f);
    return (u & 0x80000000u) ? ~u : (u | 0x80000000u);
}
__device__ __forceinline__ float unsortable(unsigned k) {
    unsigned b = (k & 0x80000000u) ? (k & 0x7FFFFFFFu) : ~k;
    return __uint_as_float(b);
}

// ---------------- radix kth-value + per-row boundary band collection --------------
// Per-row candidate segment + LDS counter (round-9's single global atomicAdd
// serialized 160K ops across 8 XCDs -> 1448us at 1.4% VALUBusy).
__global__ __launch_bounds__(256) void topk_band_kernel(const float* __restrict__ scores,
                                                        int* __restrict__ cand,
                                                        int* __restrict__ cnt) {
    int row = blockIdx.x;
    int tid = threadIdx.x;
    __shared__ unsigned s_keys[DF];
    __shared__ int hist[256];
    __shared__ int sufs[256];
    __shared__ int s_misc[4];
    __shared__ int s_cnt;

    const float* sr = scores + (size_t)row * DF;
    for (int i = tid; i < DF; i += 256) s_keys[i] = sortable(sr[i]);
    if (tid == 0) s_cnt = 0;

    unsigned prefix = 0;
    int krem = KSEL;
    for (int pass = 0; pass < 4; pass++) {
        int shift = 24 - pass * 8;
        unsigned hmask = (pass == 0) ? 0u : (0xFFFFFFFFu << (shift + 8));
        hist[tid] = 0;
        __syncthreads();
        for (int i = tid; i < DF; i += 256) {
            unsigned u = s_keys[i];
            if ((u & hmask) == prefix) atomicAdd(&hist[(u >> shift) & 0xFF], 1);
        }
        __syncthreads();
        sufs[tid] = hist[tid];
        __syncthreads();
#pragma unroll
        for (int off = 1; off < 256; off <<= 1) {
            int add = (tid + off < 256) ? sufs[tid + off] : 0;
            __syncthreads();
            sufs[tid] += add;
            __syncthreads();
        }
        if (sufs[tid] >= krem && (tid == 255 || sufs[tid + 1] < krem)) {
            s_misc[0] = tid;
            s_misc[1] = sufs[tid] - hist[tid];
        }
        __syncthreads();
        prefix |= ((unsigned)s_misc[0]) << shift;
        krem -= s_misc[1];
        __syncthreads();
    }
    float vf = unsortable(prefix);
    for (int i = tid; i < DF; i += 256) {
        float d = sr[i] - vf;
        if (__builtin_fabsf(d) <= BAND_DELTA) {
            int p = atomicAdd(&s_cnt, 1);           // LDS atomic: cheap
            if (p < CAP_ROW) cand[(size_t)row * CAP_ROW + p] = i;
        }
    }
    __syncthreads();
    if (tid == 0) cnt[row] = s_cnt < CAP_ROW ? s_cnt : CAP_ROW;
}

// ---------------- exact fp32 re-score of band candidates --------------------------
// One block per row; 4 waves stride the row's candidates (h row stays L1-hot).
__global__ __launch_bounds__(256) void rescore_kernel(const float* __restrict__ h,
                                                      const float* __restrict__ Wr2,
                                                      const int* __restrict__ cand,
                                                      const int* __restrict__ cnt,
                                                      float* __restrict__ scores) {
    int row = blockIdx.x;
    int lane = threadIdx.x & 63;
    int wv = threadIdx.x >> 6;
    int n = cnt[row];
    const float4* hp = (const float4*)(h + (size_t)row * DM);
    for (int c = wv; c < n; c += 4) {
        int col = cand[(size_t)row * CAP_ROW + c];
        const float4* wp = (const float4*)(Wr2 + (size_t)col * DM);
        float s = 0.f;
#pragma unroll
        for (int j = 0; j < 4; j++) {
            float4 a = hp[lane + 64 * j];
            float4 b = wp[lane + 64 * j];
            s = fmaf(a.x, b.x, s);
            s = fmaf(a.y, b.y, s);
            s = fmaf(a.z, b.z, s);
            s = fmaf(a.w, b.w, s);
        }
#pragma unroll
        for (int st = 1; st < 64; st <<= 1) s += __shfl_xor(s, st);
        if (lane == 0) scores[(size_t)row * DF + col] = s;
    }
}

// ---------------- top-k (k=256 of 4096) per row, exact tie-break ------------------
__global__ __launch_bounds__(256) void topk_kernel(const float* __restrict__ scores,
                                                   int* __restrict__ top_idx) {
    int row = blockIdx.x;
    int tid = threadIdx.x;
    __shared__ unsigned s_keys[DF];
    __shared__ int hist[256];
    __shared__ int sufs[256];
    __shared__ int s_misc[4];
    __shared__ int s_wsums[4];

    const float* sr = scores + (size_t)row * DF;
    for (int i = tid; i < DF; i += 256) s_keys[i] = sortable(sr[i]);

    unsigned prefix = 0;
    int krem = KSEL;
    for (int pass = 0; pass < 4; pass++) {
        int shift = 24 - pass * 8;
        unsigned hmask = (pass == 0) ? 0u : (0xFFFFFFFFu << (shift + 8));
        hist[tid] = 0;
        __syncthreads();
        for (int i = tid; i < DF; i += 256) {
            unsigned u = s_keys[i];
            if ((u & hmask) == prefix) atomicAdd(&hist[(u >> shift) & 0xFF], 1);
        }
        __syncthreads();
        sufs[tid] = hist[tid];
        __syncthreads();
#pragma unroll
        for (int off = 1; off < 256; off <<= 1) {
            int add = (tid + off < 256) ? sufs[tid + off] : 0;
            __syncthreads();
            sufs[tid] += add;
            __syncthreads();
        }
        if (sufs[tid] >= krem && (tid == 255 || sufs[tid + 1] < krem)) {
            s_misc[0] = tid;
            s_misc[1] = sufs[tid] - hist[tid];
        }
        __syncthreads();
        prefix |= ((unsigned)s_misc[0]) << shift;
        krem -= s_misc[1];
        __syncthreads();
    }
    unsigned v = prefix;
    if (tid == 0) s_misc[2] = 0;
    __syncthreads();
    int* out = top_idx + (size_t)row * KSEL;
    for (int i = tid; i < DF; i += 256) {
        if (s_keys[i] > v) {
            int p = atomicAdd(&s_misc[2], 1);
            out[p] = i;
        }
    }
    __syncthreads();
    int base = s_misc[2];
    int lane = tid & 63, wave = tid >> 6;
    int taken = 0;
    for (int chunk = 0; chunk < DF / 256; chunk++) {
        int i = chunk * 256 + tid;
        int flag = (s_keys[i] == v) ? 1 : 0;
        unsigned long long mb = __ballot(flag);
        int before = __popcll(mb & ((1ULL << lane) - 1ULL));
        if (lane == 0) s_wsums[wave] = __popcll(mb);
        __syncthreads();
        int woff = 0;
#pragma unroll
        for (int w = 0; w < 4; w++) if (w < wave) woff += s_wsums[w];
        int total = s_wsums[0] + s_wsums[1] + s_wsums[2] + s_wsums[3];
        int excl = woff + before;
        if (flag && (taken + excl) < krem) out[base + taken + excl] = i;
        taken += total;
        __syncthreads();
    }
}

// ---------------- DeepSets manifold: one block per token, one k per thread --------
__global__ __launch_bounds__(256) void manifold_kernel(
    const float* __restrict__ z, const int* __restrict__ top_idx,
    const float* __restrict__ phi1_w, const float* __restrict__ phi1_b,
    const float* __restrict__ ln1w, const float* __restrict__ ln1b,
    const float* __restrict__ phi2_w, const float* __restrict__ phi2_b,
    const float* __restrict__ ln2w, const float* __restrict__ ln2b,
    const float* __restrict__ rho1_w, const float* __restrict__ rho1_b,
    const float* __restrict__ rho2_w, const float* __restrict__ rho2_b,
    float* __restrict__ man) {
    __shared__ float s_ctxp[4 * DH];
    __shared__ float s_ctx[DH];

    int tid = threadIdx.x;
    int t = blockIdx.x;
    int lane = tid & 63, wave = tid >> 6;

    int idx = top_idx[(size_t)t * KSEL + tid];
    float a = gelu_fast(z[(size_t)t * DF + idx]);
    f32x2 a2 = {a, a};

    f32x2 gv[DH2 / 2];
    f32x2 sv = {0.f, 0.f}, qv = {0.f, 0.f};
#pragma unroll
    for (int i = 0; i < DH2 / 2; i++) {
        f32x2 w = ((const f32x2*)phi1_w)[i];
        f32x2 b = ((const f32x2*)phi1_b)[i];
        f32x2 e = pkfma(a2, w, b);
        gv[i] = e;
        sv = sv + e;
        qv = pkfma(e, e, qv);
    }
    float s = sv.x + sv.y, s2 = qv.x + qv.y;
    float mu = s * (1.0f / DH2);
    float rs = rsqrtf(s2 * (1.0f / DH2) - mu * mu + 1e-5f);
    f32x2 muv = {mu, mu}, rsv = {rs, rs};
#pragma unroll
    for (int i = 0; i < DH2 / 2; i++) {
        f32x2 t2 = (gv[i] - muv) * rsv;
        t2 = pkfma(t2, ((const f32x2*)ln1w)[i], ((const f32x2*)ln1b)[i]);
        gv[i] = (f32x2){gelu_fast(t2.x), gelu_fast(t2.y)};
    }

    f32x2 hv[DH / 2];
#pragma unroll
    for (int j2 = 0; j2 < DH / 2; j2++) {
        const f32x2* wa = (const f32x2*)(phi2_w + (2 * j2) * DH2);
        const f32x2* wb = (const f32x2*)(phi2_w + (2 * j2 + 1) * DH2);
        f32x2 ra = {phi2_b[2 * j2], 0.f};
        f32x2 rb = {phi2_b[2 * j2 + 1], 0.f};
#pragma unroll
        for (int i = 0; i < DH2 / 2; i++) {
            ra = pkfma(gv[i], wa[i], ra);
            rb = pkfma(gv[i], wb[i], rb);
        }
        hv[j2] = (f32x2){ra.x + ra.y, rb.x + rb.y};
    }

    f32x2 tsv = {0.f, 0.f}, tqv = {0.f, 0.f};
#pragma unroll
    for (int j2 = 0; j2 < DH / 2; j2++) {
        tsv = tsv + hv[j2];
        tqv = pkfma(hv[j2], hv[j2], tqv);
    }
    float tsum = tsv.x + tsv.y, tsq = tqv.x + tqv.y;
    float mu2 = tsum * (1.0f / DH);
    float rs2 = rsqrtf(tsq * (1.0f / DH) - mu2 * mu2 + 1e-5f);
    f32x2 mu2v = {mu2, mu2}, rs2v = {rs2, rs2};
#pragma unroll
    for (int j2 = 0; j2 < DH / 2; j2++) {
        f32x2 t2 = (hv[j2] - mu2v) * rs2v;
        hv[j2] = pkfma(t2, ((const f32x2*)ln2w)[j2], ((const f32x2*)ln2b)[j2]);
    }

#pragma unroll
    for (int j2 = 0; j2 < DH / 2; j2++) {
        float vx = hv[j2].x, vy = hv[j2].y;
#pragma unroll
        for (int st = 1; st < 64; st <<= 1) {
            vx += __shfl_xor(vx, st);
            vy += __shfl_xor(vy, st);
        }
        if (lane == 0) {
            s_ctxp[wave * DH + 2 * j2] = vx;
            s_ctxp[wave * DH + 2 * j2 + 1] = vy;
        }
    }
    __syncthreads();
    if (tid < DH)
        s_ctx[tid] = (s_ctxp[tid] + s_ctxp[DH + tid] + s_ctxp[2 * DH + tid] +
                      s_ctxp[3 * DH + tid]) * (1.0f / KSEL);
    __syncthreads();

#pragma unroll
    for (int j2 = 0; j2 < DH / 2; j2++) hv[j2] = hv[j2] + ((const f32x2*)s_ctx)[j2];
    float m = rho2_b[0];
    for (int p = 0; p < 2 * DH; p++) {
        const f32x2* wp = (const f32x2*)(rho1_w + p * DH);
        f32x2 r0 = {rho1_b[p], 0.f};
        f32x2 r1 = {0.f, 0.f};
#pragma unroll
        for (int q2 = 0; q2 < DH / 2; q2 += 2) {
            r0 = pkfma(hv[q2], wp[q2], r0);
            r1 = pkfma(hv[q2 + 1], wp[q2 + 1], r1);
        }
        float r = (r0.x + r0.y) + (r1.x + r1.y);
        m = fmaf(gelu_fast(r), rho2_w[p], m);
    }
    man[(size_t)t * KSEL + tid] = m;
}

// ---------------- scatter man (as bf16) into zeroed bf16 a_man --------------------
__global__ __launch_bounds__(256) void scatter_bf16_kernel(const float* __restrict__ man,
                                                           const int* __restrict__ top_idx,
                                                           short* __restrict__ a_man) {
    int t = blockIdx.x, k = threadIdx.x;
    a_man[(size_t)t * DF + top_idx[(size_t)t * KSEL + k]] =
        (short)bf16_rne(man[(size_t)t * KSEL + k]);
}

extern "C" void kernel_launch(void* const* d_in, const int* in_sizes, int n_in,
                              void* d_out, int out_size, void* d_ws, size_t ws_size,
                              hipStream_t stream) {
    const float* x      = (const float*)d_in[0];
    const float* W1     = (const float*)d_in[1];
    const float* W2     = (const float*)d_in[2];
    const float* Wr1    = (const float*)d_in[3];
    const float* Wr2    = (const float*)d_in[4];
    const float* ln_w   = (const float*)d_in[5];
    const float* ln_b   = (const float*)d_in[6];
    const float* phi1_w = (const float*)d_in[7];
    const float* phi1_b = (const float*)d_in[8];
    const float* pl1w   = (const float*)d_in[9];
    const float* pl1b   = (const float*)d_in[10];
    const float* phi2_w = (const float*)d_in[11];
    const float* phi2_b = (const float*)d_in[12];
    const float* pl2w   = (const float*)d_in[13];
    const float* pl2b   = (const float*)d_in[14];
    const float* rho1_w = (const float*)d_in[15];
    const float* rho1_b = (const float*)d_in[16];
    const float* rho2_w = (const float*)d_in[17];
    const float* rho2_b = (const float*)d_in[18];
    float* out = (float*)d_out;

    char* ws = (char*)d_ws;
    size_t off = 0;
    auto alloc = [&](size_t bytes) {
        char* p = ws + off;
        off += (bytes + 255) & ~(size_t)255;
        return p;
    };
    float* xn     = (float*)alloc(sizeof(float) * (size_t)T_TOKENS * DM);   // 16 MB
    float* h      = (float*)alloc(sizeof(float) * (size_t)T_TOKENS * DM);   // 16 MB
    float* scores = (float*)alloc(sizeof(float) * (size_t)T_TOKENS * DF);   // 64 MB
    float* z      = (float*)alloc(sizeof(float) * (size_t)T_TOKENS * DF);   // 64 MB
    int*   tidx   = (int*)alloc(sizeof(int) * (size_t)T_TOKENS * KSEL);     // 4 MB
    float* man    = (float*)alloc(sizeof(float) * (size_t)T_TOKENS * KSEL); // 4 MB
    int*   cand   = (int*)alloc(sizeof(int) * (size_t)T_TOKENS * CAP_ROW);  // 4 MB
    int*   cnt    = (int*)alloc(sizeof(int) * (size_t)T_TOKENS);            // 16 KB

    // Region reuse (stream-serial, lifetimes disjoint):
    short* h_hi   = (short*)z;                          // 8 MB (z unused until step 7)
    short* wr2_hi = (short*)z + (size_t)T_TOKENS * DM;  // next 8 MB of z
    short* xcat  = (short*)xn;      // [4096 x 2048]: [xh | xl], after router
    short* w1cat = (short*)h;       // [4096 x 2048]: [w1l | w1h], after rescore
    short* amanb = (short*)scores;  // 32 MB, after topk2
    short* w2b   = (short*)z;       // 8 MB, after manifold

    // 1. x_norm = LN(x)
    ln_kernel<<<T_TOKENS, 256, 0, stream>>>(x, ln_w, ln_b, xn);
    // 2. h = gelu(xn @ Wr1^T)   (fp32 exact — h feeds exact rescoring)
    gemm_f32_128<<<dim3(DM / 128, T_TOKENS / 128), 256, 0, stream>>>(xn, Wr1, h, T_TOKENS, DM, DM, 1);
    // 3. approx scores = h_hi @ Wr2_hi^T  (bf16 MFMA)
    cvt_bf16_kernel<<<(T_TOKENS * DM / 4 + 255) / 256, 256, 0, stream>>>(h, h_hi, T_TOKENS * DM / 4);
    cvt_bf16_kernel<<<(DF * DM / 4 + 255) / 256, 256, 0, stream>>>(Wr2, wr2_hi, DF * DM / 4);
    gemm_bf16<<<dim3(DF / 128, T_TOKENS / 128), 256, 0, stream>>>(
        h_hi, wr2_hi, scores, T_TOKENS, DF, DM, DM, DM, 0);
    // 4. per-row 256th value + boundary band (per-row segments, LDS counter)
    topk_band_kernel<<<T_TOKENS, 256, 0, stream>>>(scores, cand, cnt);
    // 5. exact fp32 re-score of band candidates, then final top-k
    rescore_kernel<<<T_TOKENS, 256, 0, stream>>>(h, Wr2, cand, cnt, scores);
    topk_kernel<<<T_TOKENS, 256, 0, stream>>>(scores, tidx);
    // 6. split x -> [xh|xl], W1 -> [w1l|w1h]
    cvt_split_cat_kernel<<<(T_TOKENS * DM / 4 + 255) / 256, 256, 0, stream>>>(x, xcat, T_TOKENS * DM / 4, 0);
    cvt_split_cat_kernel<<<(DF * DM / 4 + 255) / 256, 256, 0, stream>>>(W1, w1cat, DF * DM / 4, 1);
    // 7. z = x @ W1^T: hi*hi (K=1024) + merged cross terms (K=2048)
    gemm_bf16<<<dim3(DF / 128, T_TOKENS / 128), 256, 0, stream>>>(
        xcat, w1cat + DM, z, T_TOKENS, DF, DM, 2 * DM, 2 * DM, 0);
    gemm_bf16<<<dim3(DF / 128, T_TOKENS / 128), 256, 0, stream>>>(
        xcat, w1cat, z, T_TOKENS, DF, 2 * DM, 2 * DM, 2 * DM, 1);
    // 8. manifold
    manifold_kernel<<<T_TOKENS, 256, 0, stream>>>(z, tidx, phi1_w, phi1_b, pl1w, pl1b,
                                                  phi2_w, phi2_b, pl2w, pl2b,
                                                  rho1_w, rho1_b, rho2_w, rho2_b, man);
    // 9. scatter man -> bf16 a_man; W2 -> bf16
    hipMemsetAsync(amanb, 0, sizeof(short) * (size_t)T_TOKENS * DF, stream);
    scatter_bf16_kernel<<<T_TOKENS, 256, 0, stream>>>(man, tidx, amanb);
    cvt_bf16_kernel<<<(DM * DF / 4 + 255) / 256, 256, 0, stream>>>(W2, w2b, DM * DF / 4);
    // 10. out = a_man @ W2^T  (plain bf16 MFMA)
    gemm_bf16<<<dim3(DM / 128, T_TOKENS / 128), 256, 0, stream>>>(
        amanb, w2b, out, T_TOKENS, DM, DF, DF, DF, 0);
}

// Round 11
// 929.440 us; speedup vs baseline: 2.7695x; 1.1234x over previous
//
#include <hip/hip_runtime.h>

#define T_TOKENS 4096
#define DM 1024
#define DF 4096
#define KSEL 256
#define DH 64
#define DH2 32
#define BAND_DELTA 1.0e-2f
#define CAP_ROW 256

typedef __attribute__((ext_vector_type(8))) short short8;
typedef __attribute__((ext_vector_type(4))) float f32x4;
typedef __attribute__((ext_vector_type(2))) float f32x2;

__device__ __forceinline__ f32x2 pkfma(f32x2 a, f32x2 b, f32x2 c) {
    return __builtin_elementwise_fma(a, b, c);
}

// exact-libm gelu: ONLY for the router path
__device__ __forceinline__ float gelu_f(float x) {
    return 0.5f * x * (1.0f + erff(x * 0.70710678118654752440f));
}

// branch-free erf, Abramowitz-Stegun 7.1.26, |err| <= 1.5e-7 abs
__device__ __forceinline__ float erf_fast(float x) {
    float ax = __builtin_fabsf(x);
    float t = __builtin_amdgcn_rcpf(fmaf(0.3275911f, ax, 1.0f));
    float p = 1.061405429f;
    p = fmaf(p, t, -1.453152027f);
    p = fmaf(p, t, 1.421413741f);
    p = fmaf(p, t, -0.284496736f);
    p = fmaf(p, t, 0.254829592f);
    float e = __builtin_amdgcn_exp2f(-ax * ax * 1.44269504088896f);
    float r = fmaf(-p * t, e, 1.0f);
    return __builtin_copysignf(r, x);
}
__device__ __forceinline__ float gelu_fast(float x) {
    return 0.5f * x * (1.0f + erf_fast(x * 0.70710678118654752440f));
}

__device__ __forceinline__ unsigned short bf16_rne(float f) {
    unsigned u = __float_as_uint(f);
    unsigned r = (u + 0x7FFFu + ((u >> 16) & 1u)) >> 16;
    return (unsigned short)r;
}
__device__ __forceinline__ float bf16_to_f(unsigned short h) {
    return __uint_as_float(((unsigned)h) << 16);
}

// ---------------- LayerNorm over last dim (1024), one block per row ----------------
__global__ __launch_bounds__(256) void ln_kernel(const float* __restrict__ x,
                                                 const float* __restrict__ w,
                                                 const float* __restrict__ b,
                                                 float* __restrict__ out) {
    int row = blockIdx.x;
    int tid = threadIdx.x;
    const float4 v = ((const float4*)(x + (size_t)row * DM))[tid];
    float s = v.x + v.y + v.z + v.w;
    float s2 = v.x * v.x + v.y * v.y + v.z * v.z + v.w * v.w;
#pragma unroll
    for (int off = 32; off > 0; off >>= 1) {
        s += __shfl_xor(s, off);
        s2 += __shfl_xor(s2, off);
    }
    __shared__ float ss[4], ss2[4];
    int wave = tid >> 6;
    if ((tid & 63) == 0) { ss[wave] = s; ss2[wave] = s2; }
    __syncthreads();
    s = ss[0] + ss[1] + ss[2] + ss[3];
    s2 = ss2[0] + ss2[1] + ss2[2] + ss2[3];
    float mu = s * (1.0f / DM);
    float var = s2 * (1.0f / DM) - mu * mu;
    float rs = rsqrtf(var + 1e-5f);
    const float4 wv = ((const float4*)w)[tid];
    const float4 bv = ((const float4*)b)[tid];
    float4 o;
    o.x = (v.x - mu) * rs * wv.x + bv.x;
    o.y = (v.y - mu) * rs * wv.y + bv.y;
    o.z = (v.z - mu) * rs * wv.z + bv.z;
    o.w = (v.w - mu) * rs * wv.w + bv.w;
    ((float4*)(out + (size_t)row * DM))[tid] = o;
}

// ---------------- fp32 GEMM (router GEMM1 only) ------------------------------------
__global__ __launch_bounds__(256) void gemm_f32_128(const float* __restrict__ A,
                                                    const float* __restrict__ B,
                                                    float* __restrict__ C,
                                                    int M, int N, int K, int fuse_gelu) {
    __shared__ __align__(16) float As[16][132];
    __shared__ __align__(16) float Bs[16][132];
    int tid = threadIdx.x;
    int bm = blockIdx.y * 128, bn = blockIdx.x * 128;
    int tr = tid >> 4, tc = tid & 15;

    float4 avr[2], bvr[2];
    auto g_load = [&](int k0) {
#pragma unroll
        for (int s = 0; s < 2; s++) {
            int i = tid * 2 + s;
            int r = i >> 2, q = i & 3;
            avr[s] = *(const float4*)(A + (size_t)(bm + r) * K + k0 + q * 4);
            bvr[s] = *(const float4*)(B + (size_t)(bn + r) * K + k0 + q * 4);
        }
    };

    float acc[8][8] = {};
    g_load(0);
    for (int k0 = 0; k0 < K; k0 += 16) {
        __syncthreads();
#pragma unroll
        for (int s = 0; s < 2; s++) {
            int i = tid * 2 + s;
            int r = i >> 2, q = i & 3;
            As[q * 4 + 0][r] = avr[s].x; As[q * 4 + 1][r] = avr[s].y;
            As[q * 4 + 2][r] = avr[s].z; As[q * 4 + 3][r] = avr[s].w;
            Bs[q * 4 + 0][r] = bvr[s].x; Bs[q * 4 + 1][r] = bvr[s].y;
            Bs[q * 4 + 2][r] = bvr[s].z; Bs[q * 4 + 3][r] = bvr[s].w;
        }
        __syncthreads();
        if (k0 + 16 < K) g_load(k0 + 16);
#pragma unroll
        for (int kk = 0; kk < 16; kk++) {
            float4 a0 = *(const float4*)&As[kk][tr * 4];
            float4 a1 = *(const float4*)&As[kk][64 + tr * 4];
            float4 b0 = *(const float4*)&Bs[kk][tc * 4];
            float4 b1 = *(const float4*)&Bs[kk][64 + tc * 4];
            float ar[8] = {a0.x, a0.y, a0.z, a0.w, a1.x, a1.y, a1.z, a1.w};
            float br[8] = {b0.x, b0.y, b0.z, b0.w, b1.x, b1.y, b1.z, b1.w};
#pragma unroll
            for (int i = 0; i < 8; i++)
#pragma unroll
                for (int j = 0; j < 8; j++)
                    acc[i][j] = fmaf(ar[i], br[j], acc[i][j]);
        }
    }
#pragma unroll
    for (int i = 0; i < 8; i++) {
        int row = bm + (i < 4 ? tr * 4 + i : 64 + tr * 4 + (i - 4));
        float* cp = C + (size_t)row * N + bn;
        float4 o0, o1;
        if (fuse_gelu) {
            o0 = make_float4(gelu_f(acc[i][0]), gelu_f(acc[i][1]), gelu_f(acc[i][2]), gelu_f(acc[i][3]));
            o1 = make_float4(gelu_f(acc[i][4]), gelu_f(acc[i][5]), gelu_f(acc[i][6]), gelu_f(acc[i][7]));
        } else {
            o0 = make_float4(acc[i][0], acc[i][1], acc[i][2], acc[i][3]);
            o1 = make_float4(acc[i][4], acc[i][5], acc[i][6], acc[i][7]);
        }
        *(float4*)(cp + tc * 4) = o0;
        *(float4*)(cp + 64 + tc * 4) = o1;
    }
}

// ---------------- bf16 MFMA GEMM: C[M,N] (+)= A[M,K]*B[N,K]^T, strided rows -------
__global__ __launch_bounds__(256) void gemm_bf16(const short* __restrict__ A,
                                                 const short* __restrict__ B,
                                                 float* __restrict__ C,
                                                 int M, int N, int K,
                                                 int lda, int ldb, int beta) {
    __shared__ __align__(16) short As[128 * 64];
    __shared__ __align__(16) short Bs[128 * 64];
    int tid = threadIdx.x;
    int bm = blockIdx.y * 128, bn = blockIdx.x * 128;
    int lane = tid & 63, wave = tid >> 6;
    int wm = (wave >> 1) * 64, wn = (wave & 1) * 64;
    int quad = lane >> 4, l16 = lane & 15;
    int sr = tid >> 3, scp = tid & 7;

    short8 areg[4], breg[4];
    auto g_load = [&](int k0) {
#pragma unroll
        for (int j = 0; j < 4; j++) {
            int r = j * 32 + sr;
            int cl = scp ^ (r & 7);
            areg[j] = *(const short8*)(A + (size_t)(bm + r) * lda + k0 + cl * 8);
            breg[j] = *(const short8*)(B + (size_t)(bn + r) * ldb + k0 + cl * 8);
        }
    };

    f32x4 acc[4][4] = {};
    g_load(0);
    for (int k0 = 0; k0 < K; k0 += 64) {
        __syncthreads();
#pragma unroll
        for (int j = 0; j < 4; j++) {
            *(short8*)(As + (j * 256 + tid) * 8) = areg[j];
            *(short8*)(Bs + (j * 256 + tid) * 8) = breg[j];
        }
        __syncthreads();
        if (k0 + 64 < K) g_load(k0 + 64);
#pragma unroll
        for (int kk = 0; kk < 2; kk++) {
            short8 af[4], bf[4];
#pragma unroll
            for (int tm = 0; tm < 4; tm++) {
                int m = wm + tm * 16 + l16;
                int cp = (kk * 4 + quad) ^ (m & 7);
                af[tm] = *(const short8*)(As + m * 64 + cp * 8);
            }
#pragma unroll
            for (int tn = 0; tn < 4; tn++) {
                int n = wn + tn * 16 + l16;
                int cp = (kk * 4 + quad) ^ (n & 7);
                bf[tn] = *(const short8*)(Bs + n * 64 + cp * 8);
            }
#pragma unroll
            for (int tm = 0; tm < 4; tm++)
#pragma unroll
                for (int tn = 0; tn < 4; tn++)
                    acc[tm][tn] = __builtin_amdgcn_mfma_f32_16x16x32_bf16(
                        af[tm], bf[tn], acc[tm][tn], 0, 0, 0);
        }
    }
#pragma unroll
    for (int tm = 0; tm < 4; tm++)
#pragma unroll
        for (int tn = 0; tn < 4; tn++) {
            int row0 = bm + wm + tm * 16 + quad * 4;
            int col = bn + wn + tn * 16 + l16;
#pragma unroll
            for (int r = 0; r < 4; r++) {
                float* p = C + (size_t)(row0 + r) * N + col;
                float v = acc[tm][tn][r];
                if (beta) v += *p;
                *p = v;
            }
        }
}

// ---------------- fp32 -> concatenated (hi|lo) or (lo|hi) bf16 planes -------------
__global__ __launch_bounds__(256) void cvt_split_cat_kernel(const float* __restrict__ x,
                                                            short* __restrict__ cat,
                                                            int n4, int lo_first) {
    int i = blockIdx.x * 256 + threadIdx.x;
    if (i >= n4) return;
    float4 v = ((const float4*)x)[i];
    ushort4 h, l;
    h.x = bf16_rne(v.x); l.x = bf16_rne(v.x - bf16_to_f(h.x));
    h.y = bf16_rne(v.y); l.y = bf16_rne(v.y - bf16_to_f(h.y));
    h.z = bf16_rne(v.z); l.z = bf16_rne(v.z - bf16_to_f(h.z));
    h.w = bf16_rne(v.w); l.w = bf16_rne(v.w - bf16_to_f(h.w));
    int row = i >> 8;
    int col4 = i & 255;
    size_t base = (size_t)row * (2 * DM);
    size_t off_a = base + col4 * 4;
    size_t off_b = base + DM + col4 * 4;
    ((ushort4*)(cat + (lo_first ? off_b : off_a)))[0] = h;
    ((ushort4*)(cat + (lo_first ? off_a : off_b)))[0] = l;
}

__global__ __launch_bounds__(256) void cvt_bf16_kernel(const float* __restrict__ x,
                                                       short* __restrict__ y, int n4) {
    int i = blockIdx.x * 256 + threadIdx.x;
    if (i >= n4) return;
    float4 v = ((const float4*)x)[i];
    ushort4 h;
    h.x = bf16_rne(v.x); h.y = bf16_rne(v.y);
    h.z = bf16_rne(v.z); h.w = bf16_rne(v.w);
    ((ushort4*)y)[i] = h;
}

// ---------------- sortable-uint helpers -------------------------------------------
__device__ __forceinline__ unsigned sortable(float f) {
    unsigned u = __float_as_uint(f);
    return (u & 0x80000000u) ? ~u : (u | 0x80000000u);
}
__device__ __forceinline__ float unsortable(unsigned k) {
    unsigned b = (k & 0x80000000u) ? (k & 0x7FFFFFFFu) : ~k;
    return __uint_as_float(b);
}

// ---------------- radix kth-value + per-row boundary band collection --------------
__global__ __launch_bounds__(256) void topk_band_kernel(const float* __restrict__ scores,
                                                        int* __restrict__ cand,
                                                        int* __restrict__ cnt) {
    int row = blockIdx.x;
    int tid = threadIdx.x;
    __shared__ unsigned s_keys[DF];
    __shared__ int hist[256];
    __shared__ int sufs[256];
    __shared__ int s_misc[4];
    __shared__ int s_cnt;

    const float* sr = scores + (size_t)row * DF;
    for (int i = tid; i < DF; i += 256) s_keys[i] = sortable(sr[i]);
    if (tid == 0) s_cnt = 0;

    unsigned prefix = 0;
    int krem = KSEL;
    for (int pass = 0; pass < 4; pass++) {
        int shift = 24 - pass * 8;
        unsigned hmask = (pass == 0) ? 0u : (0xFFFFFFFFu << (shift + 8));
        hist[tid] = 0;
        __syncthreads();
        for (int i = tid; i < DF; i += 256) {
            unsigned u = s_keys[i];
            if ((u & hmask) == prefix) atomicAdd(&hist[(u >> shift) & 0xFF], 1);
        }
        __syncthreads();
        sufs[tid] = hist[tid];
        __syncthreads();
#pragma unroll
        for (int off = 1; off < 256; off <<= 1) {
            int add = (tid + off < 256) ? sufs[tid + off] : 0;
            __syncthreads();
            sufs[tid] += add;
            __syncthreads();
        }
        if (sufs[tid] >= krem && (tid == 255 || sufs[tid + 1] < krem)) {
            s_misc[0] = tid;
            s_misc[1] = sufs[tid] - hist[tid];
        }
        __syncthreads();
        prefix |= ((unsigned)s_misc[0]) << shift;
        krem -= s_misc[1];
        __syncthreads();
    }
    float vf = unsortable(prefix);
    for (int i = tid; i < DF; i += 256) {
        float d = sr[i] - vf;
        if (__builtin_fabsf(d) <= BAND_DELTA) {
            int p = atomicAdd(&s_cnt, 1);
            if (p < CAP_ROW) cand[(size_t)row * CAP_ROW + p] = i;
        }
    }
    __syncthreads();
    if (tid == 0) cnt[row] = s_cnt < CAP_ROW ? s_cnt : CAP_ROW;
}

// ---------------- exact fp32 re-score of band candidates --------------------------
__global__ __launch_bounds__(256) void rescore_kernel(const float* __restrict__ h,
                                                      const float* __restrict__ Wr2,
                                                      const int* __restrict__ cand,
                                                      const int* __restrict__ cnt,
                                                      float* __restrict__ scores) {
    int row = blockIdx.x;
    int lane = threadIdx.x & 63;
    int wv = threadIdx.x >> 6;
    int n = cnt[row];
    const float4* hp = (const float4*)(h + (size_t)row * DM);
    for (int c = wv; c < n; c += 4) {
        int col = cand[(size_t)row * CAP_ROW + c];
        const float4* wp = (const float4*)(Wr2 + (size_t)col * DM);
        float s = 0.f;
#pragma unroll
        for (int j = 0; j < 4; j++) {
            float4 a = hp[lane + 64 * j];
            float4 b = wp[lane + 64 * j];
            s = fmaf(a.x, b.x, s);
            s = fmaf(a.y, b.y, s);
            s = fmaf(a.z, b.z, s);
            s = fmaf(a.w, b.w, s);
        }
#pragma unroll
        for (int st = 1; st < 64; st <<= 1) s += __shfl_xor(s, st);
        if (lane == 0) scores[(size_t)row * DF + col] = s;
    }
}

// ---------------- top-k (k=256 of 4096) per row, exact tie-break ------------------
__global__ __launch_bounds__(256) void topk_kernel(const float* __restrict__ scores,
                                                   int* __restrict__ top_idx) {
    int row = blockIdx.x;
    int tid = threadIdx.x;
    __shared__ unsigned s_keys[DF];
    __shared__ int hist[256];
    __shared__ int sufs[256];
    __shared__ int s_misc[4];
    __shared__ int s_wsums[4];

    const float* sr = scores + (size_t)row * DF;
    for (int i = tid; i < DF; i += 256) s_keys[i] = sortable(sr[i]);

    unsigned prefix = 0;
    int krem = KSEL;
    for (int pass = 0; pass < 4; pass++) {
        int shift = 24 - pass * 8;
        unsigned hmask = (pass == 0) ? 0u : (0xFFFFFFFFu << (shift + 8));
        hist[tid] = 0;
        __syncthreads();
        for (int i = tid; i < DF; i += 256) {
            unsigned u = s_keys[i];
            if ((u & hmask) == prefix) atomicAdd(&hist[(u >> shift) & 0xFF], 1);
        }
        __syncthreads();
        sufs[tid] = hist[tid];
        __syncthreads();
#pragma unroll
        for (int off = 1; off < 256; off <<= 1) {
            int add = (tid + off < 256) ? sufs[tid + off] : 0;
            __syncthreads();
            sufs[tid] += add;
            __syncthreads();
        }
        if (sufs[tid] >= krem && (tid == 255 || sufs[tid + 1] < krem)) {
            s_misc[0] = tid;
            s_misc[1] = sufs[tid] - hist[tid];
        }
        __syncthreads();
        prefix |= ((unsigned)s_misc[0]) << shift;
        krem -= s_misc[1];
        __syncthreads();
    }
    unsigned v = prefix;
    if (tid == 0) s_misc[2] = 0;
    __syncthreads();
    int* out = top_idx + (size_t)row * KSEL;
    for (int i = tid; i < DF; i += 256) {
        if (s_keys[i] > v) {
            int p = atomicAdd(&s_misc[2], 1);
            out[p] = i;
        }
    }
    __syncthreads();
    int base = s_misc[2];
    int lane = tid & 63, wave = tid >> 6;
    int taken = 0;
    for (int chunk = 0; chunk < DF / 256; chunk++) {
        int i = chunk * 256 + tid;
        int flag = (s_keys[i] == v) ? 1 : 0;
        unsigned long long mb = __ballot(flag);
        int before = __popcll(mb & ((1ULL << lane) - 1ULL));
        if (lane == 0) s_wsums[wave] = __popcll(mb);
        __syncthreads();
        int woff = 0;
#pragma unroll
        for (int w = 0; w < 4; w++) if (w < wave) woff += s_wsums[w];
        int total = s_wsums[0] + s_wsums[1] + s_wsums[2] + s_wsums[3];
        int excl = woff + before;
        if (flag && (taken + excl) < krem) out[base + taken + excl] = i;
        taken += total;
        __syncthreads();
    }
}

// ---------------- DeepSets manifold: MFMA rho1 ------------------------------------
// Per token-block: per-thread phi1/LN1/gelu/phi2/LN2/ctx as before; then c packed
// bf16 into XOR-swizzled LDS and rho1 done as 64 MFMAs/wave (layout identical to
// gemm_bf16's validated fragment scheme). Kills the 4096-AGPR-read rho1 loop.
__global__ __launch_bounds__(256) void manifold_kernel(
    const float* __restrict__ z, const int* __restrict__ top_idx,
    const float* __restrict__ phi1_w, const float* __restrict__ phi1_b,
    const float* __restrict__ ln1w, const float* __restrict__ ln1b,
    const float* __restrict__ phi2_w, const float* __restrict__ phi2_b,
    const float* __restrict__ ln2w, const float* __restrict__ ln2b,
    const short* __restrict__ rho1b16, const float* __restrict__ rho1_b,
    const float* __restrict__ rho2_w, const float* __restrict__ rho2_b,
    float* __restrict__ man) {
    __shared__ __align__(16) short c_lds[256 * DH];   // 32 KB
    __shared__ __align__(16) short w_lds[128 * DH];   // 16 KB
    __shared__ float s_ctxp[4 * DH];
    __shared__ float s_ctx[DH];
    __shared__ float s_rho1b[2 * DH];
    __shared__ float s_rho2w[2 * DH];

    int tid = threadIdx.x;
    int t = blockIdx.x;
    int lane = tid & 63, wave = tid >> 6;
    int l16 = lane & 15, quad = lane >> 4;

    // stage rho1 (bf16, row-swizzled) + rho1_b + rho2_w
    for (int b = tid; b < 128 * 8; b += 256) {
        int row = b >> 3, j = b & 7;
        *(short8*)(w_lds + row * DH + ((j ^ (row & 7)) * 8)) =
            *(const short8*)(rho1b16 + row * DH + j * 8);
    }
    if (tid < 2 * DH) { s_rho1b[tid] = rho1_b[tid]; s_rho2w[tid] = rho2_w[tid]; }

    int idx = top_idx[(size_t)t * KSEL + tid];
    float a = gelu_fast(z[(size_t)t * DF + idx]);
    f32x2 a2 = {a, a};

    f32x2 gv[DH2 / 2];
    f32x2 sv = {0.f, 0.f}, qv = {0.f, 0.f};
#pragma unroll
    for (int i = 0; i < DH2 / 2; i++) {
        f32x2 w = ((const f32x2*)phi1_w)[i];
        f32x2 b = ((const f32x2*)phi1_b)[i];
        f32x2 e = pkfma(a2, w, b);
        gv[i] = e;
        sv = sv + e;
        qv = pkfma(e, e, qv);
    }
    float s = sv.x + sv.y, s2 = qv.x + qv.y;
    float mu = s * (1.0f / DH2);
    float rs = rsqrtf(s2 * (1.0f / DH2) - mu * mu + 1e-5f);
    f32x2 muv = {mu, mu}, rsv = {rs, rs};
#pragma unroll
    for (int i = 0; i < DH2 / 2; i++) {
        f32x2 t2 = (gv[i] - muv) * rsv;
        t2 = pkfma(t2, ((const f32x2*)ln1w)[i], ((const f32x2*)ln1b)[i]);
        gv[i] = (f32x2){gelu_fast(t2.x), gelu_fast(t2.y)};
    }

    f32x2 hv[DH / 2];
#pragma unroll
    for (int j2 = 0; j2 < DH / 2; j2++) {
        const f32x2* wa = (const f32x2*)(phi2_w + (2 * j2) * DH2);
        const f32x2* wb = (const f32x2*)(phi2_w + (2 * j2 + 1) * DH2);
        f32x2 ra = {phi2_b[2 * j2], 0.f};
        f32x2 rb = {phi2_b[2 * j2 + 1], 0.f};
#pragma unroll
        for (int i = 0; i < DH2 / 2; i++) {
            ra = pkfma(gv[i], wa[i], ra);
            rb = pkfma(gv[i], wb[i], rb);
        }
        hv[j2] = (f32x2){ra.x + ra.y, rb.x + rb.y};
    }

    f32x2 tsv = {0.f, 0.f}, tqv = {0.f, 0.f};
#pragma unroll
    for (int j2 = 0; j2 < DH / 2; j2++) {
        tsv = tsv + hv[j2];
        tqv = pkfma(hv[j2], hv[j2], tqv);
    }
    float tsum = tsv.x + tsv.y, tsq = tqv.x + tqv.y;
    float mu2 = tsum * (1.0f / DH);
    float rs2 = rsqrtf(tsq * (1.0f / DH) - mu2 * mu2 + 1e-5f);
    f32x2 mu2v = {mu2, mu2}, rs2v = {rs2, rs2};
#pragma unroll
    for (int j2 = 0; j2 < DH / 2; j2++) {
        f32x2 t2 = (hv[j2] - mu2v) * rs2v;
        hv[j2] = pkfma(t2, ((const f32x2*)ln2w)[j2], ((const f32x2*)ln2b)[j2]);
    }

#pragma unroll
    for (int j2 = 0; j2 < DH / 2; j2++) {
        float vx = hv[j2].x, vy = hv[j2].y;
#pragma unroll
        for (int st = 1; st < 64; st <<= 1) {
            vx += __shfl_xor(vx, st);
            vy += __shfl_xor(vy, st);
        }
        if (lane == 0) {
            s_ctxp[wave * DH + 2 * j2] = vx;
            s_ctxp[wave * DH + 2 * j2 + 1] = vy;
        }
    }
    __syncthreads();
    if (tid < DH)
        s_ctx[tid] = (s_ctxp[tid] + s_ctxp[DH + tid] + s_ctxp[2 * DH + tid] +
                      s_ctxp[3 * DH + tid]) * (1.0f / KSEL);
    __syncthreads();

    // c = e64 + ctx -> bf16 -> swizzled LDS row (thread tid = k-row)
#pragma unroll
    for (int j = 0; j < 8; j++) {
        short8 pk;
#pragma unroll
        for (int i2 = 0; i2 < 4; i2++) {
            f32x2 v = hv[4 * j + i2] + ((const f32x2*)s_ctx)[4 * j + i2];
            pk[2 * i2] = (short)bf16_rne(v.x);
            pk[2 * i2 + 1] = (short)bf16_rne(v.y);
        }
        *(short8*)(c_lds + tid * DH + ((j ^ (tid & 7)) * 8)) = pk;
    }
    __syncthreads();

    // MFMA: wave handles k-rows [wave*64, wave*64+64), all 128 p-cols
    int wbase = wave * 64;
    short8 af[4][2];
#pragma unroll
    for (int tm = 0; tm < 4; tm++)
#pragma unroll
        for (int kf = 0; kf < 2; kf++) {
            int m = wbase + tm * 16 + l16;
            int cl = (kf * 4 + quad) ^ (m & 7);
            af[tm][kf] = *(const short8*)(c_lds + m * DH + cl * 8);
        }
    float mpart[4][4] = {};
#pragma unroll
    for (int tn = 0; tn < 8; tn++) {
        int n = tn * 16 + l16;
        short8 bf[2];
#pragma unroll
        for (int kf = 0; kf < 2; kf++) {
            int cl = (kf * 4 + quad) ^ (n & 7);
            bf[kf] = *(const short8*)(w_lds + n * DH + cl * 8);
        }
        f32x4 acc[4] = {};
#pragma unroll
        for (int kf = 0; kf < 2; kf++)
#pragma unroll
            for (int tm = 0; tm < 4; tm++)
                acc[tm] = __builtin_amdgcn_mfma_f32_16x16x32_bf16(
                    af[tm][kf], bf[kf], acc[tm], 0, 0, 0);
        float b1 = s_rho1b[n];   // C-layout: col = l16 = p within tile
        float w2v = s_rho2w[n];
#pragma unroll
        for (int tm = 0; tm < 4; tm++)
#pragma unroll
            for (int r = 0; r < 4; r++)
                mpart[tm][r] = fmaf(gelu_fast(acc[tm][r] + b1), w2v, mpart[tm][r]);
    }
    // reduce over the 16 p-cols (lane bits 0..3), then lane l16==0 writes
#pragma unroll
    for (int tm = 0; tm < 4; tm++)
#pragma unroll
        for (int r = 0; r < 4; r++) {
            float v = mpart[tm][r];
            v += __shfl_xor(v, 1);
            v += __shfl_xor(v, 2);
            v += __shfl_xor(v, 4);
            v += __shfl_xor(v, 8);
            mpart[tm][r] = v;
        }
    if (l16 == 0) {
        float b2 = rho2_b[0];
#pragma unroll
        for (int tm = 0; tm < 4; tm++)
#pragma unroll
            for (int r = 0; r < 4; r++)
                man[(size_t)t * KSEL + wbase + tm * 16 + quad * 4 + r] =
                    mpart[tm][r] + b2;
    }
}

// ---------------- scatter man (as bf16) into zeroed bf16 a_man --------------------
__global__ __launch_bounds__(256) void scatter_bf16_kernel(const float* __restrict__ man,
                                                           const int* __restrict__ top_idx,
                                                           short* __restrict__ a_man) {
    int t = blockIdx.x, k = threadIdx.x;
    a_man[(size_t)t * DF + top_idx[(size_t)t * KSEL + k]] =
        (short)bf16_rne(man[(size_t)t * KSEL + k]);
}

extern "C" void kernel_launch(void* const* d_in, const int* in_sizes, int n_in,
                              void* d_out, int out_size, void* d_ws, size_t ws_size,
                              hipStream_t stream) {
    const float* x      = (const float*)d_in[0];
    const float* W1     = (const float*)d_in[1];
    const float* W2     = (const float*)d_in[2];
    const float* Wr1    = (const float*)d_in[3];
    const float* Wr2    = (const float*)d_in[4];
    const float* ln_w   = (const float*)d_in[5];
    const float* ln_b   = (const float*)d_in[6];
    const float* phi1_w = (const float*)d_in[7];
    const float* phi1_b = (const float*)d_in[8];
    const float* pl1w   = (const float*)d_in[9];
    const float* pl1b   = (const float*)d_in[10];
    const float* phi2_w = (const float*)d_in[11];
    const float* phi2_b = (const float*)d_in[12];
    const float* pl2w   = (const float*)d_in[13];
    const float* pl2b   = (const float*)d_in[14];
    const float* rho1_w = (const float*)d_in[15];
    const float* rho1_b = (const float*)d_in[16];
    const float* rho2_w = (const float*)d_in[17];
    const float* rho2_b = (const float*)d_in[18];
    float* out = (float*)d_out;

    char* ws = (char*)d_ws;
    size_t off = 0;
    auto alloc = [&](size_t bytes) {
        char* p = ws + off;
        off += (bytes + 255) & ~(size_t)255;
        return p;
    };
    float* xn     = (float*)alloc(sizeof(float) * (size_t)T_TOKENS * DM);   // 16 MB
    float* h      = (float*)alloc(sizeof(float) * (size_t)T_TOKENS * DM);   // 16 MB
    float* scores = (float*)alloc(sizeof(float) * (size_t)T_TOKENS * DF);   // 64 MB
    float* z      = (float*)alloc(sizeof(float) * (size_t)T_TOKENS * DF);   // 64 MB
    int*   tidx   = (int*)alloc(sizeof(int) * (size_t)T_TOKENS * KSEL);     // 4 MB
    float* man    = (float*)alloc(sizeof(float) * (size_t)T_TOKENS * KSEL); // 4 MB
    int*   cand   = (int*)alloc(sizeof(int) * (size_t)T_TOKENS * CAP_ROW);  // 4 MB
    int*   cnt    = (int*)alloc(sizeof(int) * (size_t)T_TOKENS);            // 16 KB
    short* rho1b16 = (short*)alloc(sizeof(short) * 2 * DH * DH);            // 16 KB

    // Region reuse (stream-serial, lifetimes disjoint):
    short* h_hi   = (short*)z;                          // 8 MB (z unused until step 7)
    short* wr2_hi = (short*)z + (size_t)T_TOKENS * DM;  // next 8 MB of z
    short* xcat  = (short*)xn;      // [4096 x 2048]: [xh | xl], after router
    short* w1cat = (short*)h;       // [4096 x 2048]: [w1l | w1h], after rescore
    short* amanb = (short*)scores;  // 32 MB, after topk2
    short* w2b   = (short*)z;       // 8 MB, after manifold

    // 1. x_norm = LN(x)
    ln_kernel<<<T_TOKENS, 256, 0, stream>>>(x, ln_w, ln_b, xn);
    // 2. h = gelu(xn @ Wr1^T)   (fp32 exact — h feeds exact rescoring)
    gemm_f32_128<<<dim3(DM / 128, T_TOKENS / 128), 256, 0, stream>>>(xn, Wr1, h, T_TOKENS, DM, DM, 1);
    // 3. approx scores = h_hi @ Wr2_hi^T  (bf16 MFMA)
    cvt_bf16_kernel<<<(T_TOKENS * DM / 4 + 255) / 256, 256, 0, stream>>>(h, h_hi, T_TOKENS * DM / 4);
    cvt_bf16_kernel<<<(DF * DM / 4 + 255) / 256, 256, 0, stream>>>(Wr2, wr2_hi, DF * DM / 4);
    gemm_bf16<<<dim3(DF / 128, T_TOKENS / 128), 256, 0, stream>>>(
        h_hi, wr2_hi, scores, T_TOKENS, DF, DM, DM, DM, 0);
    // 4. per-row 256th value + boundary band (per-row segments, LDS counter)
    topk_band_kernel<<<T_TOKENS, 256, 0, stream>>>(scores, cand, cnt);
    // 5. exact fp32 re-score of band candidates, then final top-k
    rescore_kernel<<<T_TOKENS, 256, 0, stream>>>(h, Wr2, cand, cnt, scores);
    topk_kernel<<<T_TOKENS, 256, 0, stream>>>(scores, tidx);
    // 6. split x -> [xh|xl], W1 -> [w1l|w1h]; rho1 -> bf16
    cvt_split_cat_kernel<<<(T_TOKENS * DM / 4 + 255) / 256, 256, 0, stream>>>(x, xcat, T_TOKENS * DM / 4, 0);
    cvt_split_cat_kernel<<<(DF * DM / 4 + 255) / 256, 256, 0, stream>>>(W1, w1cat, DF * DM / 4, 1);
    cvt_bf16_kernel<<<(2 * DH * DH / 4 + 255) / 256, 256, 0, stream>>>(rho1_w, rho1b16, 2 * DH * DH / 4);
    // 7. z = x @ W1^T: hi*hi (K=1024) + merged cross terms (K=2048)
    gemm_bf16<<<dim3(DF / 128, T_TOKENS / 128), 256, 0, stream>>>(
        xcat, w1cat + DM, z, T_TOKENS, DF, DM, 2 * DM, 2 * DM, 0);
    gemm_bf16<<<dim3(DF / 128, T_TOKENS / 128), 256, 0, stream>>>(
        xcat, w1cat, z, T_TOKENS, DF, 2 * DM, 2 * DM, 2 * DM, 1);
    // 8. manifold (MFMA rho1)
    manifold_kernel<<<T_TOKENS, 256, 0, stream>>>(z, tidx, phi1_w, phi1_b, pl1w, pl1b,
                                                  phi2_w, phi2_b, pl2w, pl2b,
                                                  rho1b16, rho1_b, rho2_w, rho2_b, man);
    // 9. scatter man -> bf16 a_man; W2 -> bf16
    hipMemsetAsync(amanb, 0, sizeof(short) * (size_t)T_TOKENS * DF, stream);
    scatter_bf16_kernel<<<T_TOKENS, 256, 0, stream>>>(man, tidx, amanb);
    cvt_bf16_kernel<<<(DM * DF / 4 + 255) / 256, 256, 0, stream>>>(W2, w2b, DM * DF / 4);
    // 10. out = a_man @ W2^T  (plain bf16 MFMA)
    gemm_bf16<<<dim3(DM / 128, T_TOKENS / 128), 256, 0, stream>>>(
        amanb, w2b, out, T_TOKENS, DM, DF, DF, DF, 0);
}

// Round 12
// 775.951 us; speedup vs baseline: 3.3173x; 1.1978x over previous
//
#include <hip/hip_runtime.h>

#define T_TOKENS 4096
#define DM 1024
#define DF 4096
#define KSEL 256
#define DH 64
#define DH2 32
#define BAND_DELTA 1.0e-2f
#define CAP_ROW 256

typedef __attribute__((ext_vector_type(8))) short short8;
typedef __attribute__((ext_vector_type(8))) _Float16 half8;
typedef __attribute__((ext_vector_type(4))) float f32x4;
typedef __attribute__((ext_vector_type(2))) float f32x2;

__device__ __forceinline__ f32x2 pkfma(f32x2 a, f32x2 b, f32x2 c) {
    return __builtin_elementwise_fma(a, b, c);
}

// exact-libm gelu: ONLY for the router path
__device__ __forceinline__ float gelu_f(float x) {
    return 0.5f * x * (1.0f + erff(x * 0.70710678118654752440f));
}

// branch-free erf, Abramowitz-Stegun 7.1.26, |err| <= 1.5e-7 abs
__device__ __forceinline__ float erf_fast(float x) {
    float ax = __builtin_fabsf(x);
    float t = __builtin_amdgcn_rcpf(fmaf(0.3275911f, ax, 1.0f));
    float p = 1.061405429f;
    p = fmaf(p, t, -1.453152027f);
    p = fmaf(p, t, 1.421413741f);
    p = fmaf(p, t, -0.284496736f);
    p = fmaf(p, t, 0.254829592f);
    float e = __builtin_amdgcn_exp2f(-ax * ax * 1.44269504088896f);
    float r = fmaf(-p * t, e, 1.0f);
    return __builtin_copysignf(r, x);
}
__device__ __forceinline__ float gelu_fast(float x) {
    return 0.5f * x * (1.0f + erf_fast(x * 0.70710678118654752440f));
}

__device__ __forceinline__ unsigned short bf16_rne(float f) {
    unsigned u = __float_as_uint(f);
    unsigned r = (u + 0x7FFFu + ((u >> 16) & 1u)) >> 16;
    return (unsigned short)r;
}

// ---------------- LayerNorm over last dim (1024), one block per row ----------------
__global__ __launch_bounds__(256) void ln_kernel(const float* __restrict__ x,
                                                 const float* __restrict__ w,
                                                 const float* __restrict__ b,
                                                 float* __restrict__ out) {
    int row = blockIdx.x;
    int tid = threadIdx.x;
    const float4 v = ((const float4*)(x + (size_t)row * DM))[tid];
    float s = v.x + v.y + v.z + v.w;
    float s2 = v.x * v.x + v.y * v.y + v.z * v.z + v.w * v.w;
#pragma unroll
    for (int off = 32; off > 0; off >>= 1) {
        s += __shfl_xor(s, off);
        s2 += __shfl_xor(s2, off);
    }
    __shared__ float ss[4], ss2[4];
    int wave = tid >> 6;
    if ((tid & 63) == 0) { ss[wave] = s; ss2[wave] = s2; }
    __syncthreads();
    s = ss[0] + ss[1] + ss[2] + ss[3];
    s2 = ss2[0] + ss2[1] + ss2[2] + ss2[3];
    float mu = s * (1.0f / DM);
    float var = s2 * (1.0f / DM) - mu * mu;
    float rs = rsqrtf(var + 1e-5f);
    const float4 wv = ((const float4*)w)[tid];
    const float4 bv = ((const float4*)b)[tid];
    float4 o;
    o.x = (v.x - mu) * rs * wv.x + bv.x;
    o.y = (v.y - mu) * rs * wv.y + bv.y;
    o.z = (v.z - mu) * rs * wv.z + bv.z;
    o.w = (v.w - mu) * rs * wv.w + bv.w;
    ((float4*)(out + (size_t)row * DM))[tid] = o;
}

// ---------------- fp32 GEMM (router GEMM1 only) ------------------------------------
__global__ __launch_bounds__(256) void gemm_f32_128(const float* __restrict__ A,
                                                    const float* __restrict__ B,
                                                    float* __restrict__ C,
                                                    int M, int N, int K, int fuse_gelu) {
    __shared__ __align__(16) float As[16][132];
    __shared__ __align__(16) float Bs[16][132];
    int tid = threadIdx.x;
    int bm = blockIdx.y * 128, bn = blockIdx.x * 128;
    int tr = tid >> 4, tc = tid & 15;

    float4 avr[2], bvr[2];
    auto g_load = [&](int k0) {
#pragma unroll
        for (int s = 0; s < 2; s++) {
            int i = tid * 2 + s;
            int r = i >> 2, q = i & 3;
            avr[s] = *(const float4*)(A + (size_t)(bm + r) * K + k0 + q * 4);
            bvr[s] = *(const float4*)(B + (size_t)(bn + r) * K + k0 + q * 4);
        }
    };

    float acc[8][8] = {};
    g_load(0);
    for (int k0 = 0; k0 < K; k0 += 16) {
        __syncthreads();
#pragma unroll
        for (int s = 0; s < 2; s++) {
            int i = tid * 2 + s;
            int r = i >> 2, q = i & 3;
            As[q * 4 + 0][r] = avr[s].x; As[q * 4 + 1][r] = avr[s].y;
            As[q * 4 + 2][r] = avr[s].z; As[q * 4 + 3][r] = avr[s].w;
            Bs[q * 4 + 0][r] = bvr[s].x; Bs[q * 4 + 1][r] = bvr[s].y;
            Bs[q * 4 + 2][r] = bvr[s].z; Bs[q * 4 + 3][r] = bvr[s].w;
        }
        __syncthreads();
        if (k0 + 16 < K) g_load(k0 + 16);
#pragma unroll
        for (int kk = 0; kk < 16; kk++) {
            float4 a0 = *(const float4*)&As[kk][tr * 4];
            float4 a1 = *(const float4*)&As[kk][64 + tr * 4];
            float4 b0 = *(const float4*)&Bs[kk][tc * 4];
            float4 b1 = *(const float4*)&Bs[kk][64 + tc * 4];
            float ar[8] = {a0.x, a0.y, a0.z, a0.w, a1.x, a1.y, a1.z, a1.w};
            float br[8] = {b0.x, b0.y, b0.z, b0.w, b1.x, b1.y, b1.z, b1.w};
#pragma unroll
            for (int i = 0; i < 8; i++)
#pragma unroll
                for (int j = 0; j < 8; j++)
                    acc[i][j] = fmaf(ar[i], br[j], acc[i][j]);
        }
    }
#pragma unroll
    for (int i = 0; i < 8; i++) {
        int row = bm + (i < 4 ? tr * 4 + i : 64 + tr * 4 + (i - 4));
        float* cp = C + (size_t)row * N + bn;
        float4 o0, o1;
        if (fuse_gelu) {
            o0 = make_float4(gelu_f(acc[i][0]), gelu_f(acc[i][1]), gelu_f(acc[i][2]), gelu_f(acc[i][3]));
            o1 = make_float4(gelu_f(acc[i][4]), gelu_f(acc[i][5]), gelu_f(acc[i][6]), gelu_f(acc[i][7]));
        } else {
            o0 = make_float4(acc[i][0], acc[i][1], acc[i][2], acc[i][3]);
            o1 = make_float4(acc[i][4], acc[i][5], acc[i][6], acc[i][7]);
        }
        *(float4*)(cp + tc * 4) = o0;
        *(float4*)(cp + 64 + tc * 4) = o1;
    }
}

// ---------------- bf16 MFMA GEMM (approx scores) ----------------------------------
__global__ __launch_bounds__(256) void gemm_bf16(const short* __restrict__ A,
                                                 const short* __restrict__ B,
                                                 float* __restrict__ C,
                                                 int M, int N, int K,
                                                 int lda, int ldb, int beta) {
    __shared__ __align__(16) short As[128 * 64];
    __shared__ __align__(16) short Bs[128 * 64];
    int tid = threadIdx.x;
    int bm = blockIdx.y * 128, bn = blockIdx.x * 128;
    int lane = tid & 63, wave = tid >> 6;
    int wm = (wave >> 1) * 64, wn = (wave & 1) * 64;
    int quad = lane >> 4, l16 = lane & 15;
    int sr = tid >> 3, scp = tid & 7;

    short8 areg[4], breg[4];
    auto g_load = [&](int k0) {
#pragma unroll
        for (int j = 0; j < 4; j++) {
            int r = j * 32 + sr;
            int cl = scp ^ (r & 7);
            areg[j] = *(const short8*)(A + (size_t)(bm + r) * lda + k0 + cl * 8);
            breg[j] = *(const short8*)(B + (size_t)(bn + r) * ldb + k0 + cl * 8);
        }
    };

    f32x4 acc[4][4] = {};
    g_load(0);
    for (int k0 = 0; k0 < K; k0 += 64) {
        __syncthreads();
#pragma unroll
        for (int j = 0; j < 4; j++) {
            *(short8*)(As + (j * 256 + tid) * 8) = areg[j];
            *(short8*)(Bs + (j * 256 + tid) * 8) = breg[j];
        }
        __syncthreads();
        if (k0 + 64 < K) g_load(k0 + 64);
#pragma unroll
        for (int kk = 0; kk < 2; kk++) {
            short8 af[4], bf[4];
#pragma unroll
            for (int tm = 0; tm < 4; tm++) {
                int m = wm + tm * 16 + l16;
                int cp = (kk * 4 + quad) ^ (m & 7);
                af[tm] = *(const short8*)(As + m * 64 + cp * 8);
            }
#pragma unroll
            for (int tn = 0; tn < 4; tn++) {
                int n = wn + tn * 16 + l16;
                int cp = (kk * 4 + quad) ^ (n & 7);
                bf[tn] = *(const short8*)(Bs + n * 64 + cp * 8);
            }
#pragma unroll
            for (int tm = 0; tm < 4; tm++)
#pragma unroll
                for (int tn = 0; tn < 4; tn++)
                    acc[tm][tn] = __builtin_amdgcn_mfma_f32_16x16x32_bf16(
                        af[tm], bf[tn], acc[tm][tn], 0, 0, 0);
        }
    }
#pragma unroll
    for (int tm = 0; tm < 4; tm++)
#pragma unroll
        for (int tn = 0; tn < 4; tn++) {
            int row0 = bm + wm + tm * 16 + quad * 4;
            int col = bn + wn + tn * 16 + l16;
#pragma unroll
            for (int r = 0; r < 4; r++) {
                float* p = C + (size_t)(row0 + r) * N + col;
                float v = acc[tm][tn][r];
                if (beta) v += *p;
                *p = v;
            }
        }
}

// ---------------- fp16 MFMA GEMM (z and out: 4x finer mantissa, same rate) --------
__global__ __launch_bounds__(256) void gemm_f16(const short* __restrict__ A,
                                                const short* __restrict__ B,
                                                float* __restrict__ C,
                                                int M, int N, int K,
                                                int lda, int ldb) {
    __shared__ __align__(16) short As[128 * 64];
    __shared__ __align__(16) short Bs[128 * 64];
    int tid = threadIdx.x;
    int bm = blockIdx.y * 128, bn = blockIdx.x * 128;
    int lane = tid & 63, wave = tid >> 6;
    int wm = (wave >> 1) * 64, wn = (wave & 1) * 64;
    int quad = lane >> 4, l16 = lane & 15;
    int sr = tid >> 3, scp = tid & 7;

    short8 areg[4], breg[4];
    auto g_load = [&](int k0) {
#pragma unroll
        for (int j = 0; j < 4; j++) {
            int r = j * 32 + sr;
            int cl = scp ^ (r & 7);
            areg[j] = *(const short8*)(A + (size_t)(bm + r) * lda + k0 + cl * 8);
            breg[j] = *(const short8*)(B + (size_t)(bn + r) * ldb + k0 + cl * 8);
        }
    };

    f32x4 acc[4][4] = {};
    g_load(0);
    for (int k0 = 0; k0 < K; k0 += 64) {
        __syncthreads();
#pragma unroll
        for (int j = 0; j < 4; j++) {
            *(short8*)(As + (j * 256 + tid) * 8) = areg[j];
            *(short8*)(Bs + (j * 256 + tid) * 8) = breg[j];
        }
        __syncthreads();
        if (k0 + 64 < K) g_load(k0 + 64);
#pragma unroll
        for (int kk = 0; kk < 2; kk++) {
            short8 af[4], bf[4];
#pragma unroll
            for (int tm = 0; tm < 4; tm++) {
                int m = wm + tm * 16 + l16;
                int cp = (kk * 4 + quad) ^ (m & 7);
                af[tm] = *(const short8*)(As + m * 64 + cp * 8);
            }
#pragma unroll
            for (int tn = 0; tn < 4; tn++) {
                int n = wn + tn * 16 + l16;
                int cp = (kk * 4 + quad) ^ (n & 7);
                bf[tn] = *(const short8*)(Bs + n * 64 + cp * 8);
            }
#pragma unroll
            for (int tm = 0; tm < 4; tm++)
#pragma unroll
                for (int tn = 0; tn < 4; tn++)
                    acc[tm][tn] = __builtin_amdgcn_mfma_f32_16x16x32_f16(
                        __builtin_bit_cast(half8, af[tm]),
                        __builtin_bit_cast(half8, bf[tn]), acc[tm][tn], 0, 0, 0);
        }
    }
#pragma unroll
    for (int tm = 0; tm < 4; tm++)
#pragma unroll
        for (int tn = 0; tn < 4; tn++) {
            int row0 = bm + wm + tm * 16 + quad * 4;
            int col = bn + wn + tn * 16 + l16;
#pragma unroll
            for (int r = 0; r < 4; r++)
                C[(size_t)(row0 + r) * N + col] = acc[tm][tn][r];
        }
}

// ---------------- converters ------------------------------------------------------
__global__ __launch_bounds__(256) void cvt_bf16_kernel(const float* __restrict__ x,
                                                       short* __restrict__ y, int n4) {
    int i = blockIdx.x * 256 + threadIdx.x;
    if (i >= n4) return;
    float4 v = ((const float4*)x)[i];
    ushort4 h;
    h.x = bf16_rne(v.x); h.y = bf16_rne(v.y);
    h.z = bf16_rne(v.z); h.w = bf16_rne(v.w);
    ((ushort4*)y)[i] = h;
}

__global__ __launch_bounds__(256) void cvt_f16_kernel(const float* __restrict__ x,
                                                      short* __restrict__ y, int n4) {
    int i = blockIdx.x * 256 + threadIdx.x;
    if (i >= n4) return;
    float4 v = ((const float4*)x)[i];
    ushort4 h;
    h.x = __builtin_bit_cast(unsigned short, (_Float16)v.x);
    h.y = __builtin_bit_cast(unsigned short, (_Float16)v.y);
    h.z = __builtin_bit_cast(unsigned short, (_Float16)v.z);
    h.w = __builtin_bit_cast(unsigned short, (_Float16)v.w);
    ((ushort4*)y)[i] = h;
}

// ---------------- sortable-uint helpers -------------------------------------------
__device__ __forceinline__ unsigned sortable(float f) {
    unsigned u = __float_as_uint(f);
    return (u & 0x80000000u) ? ~u : (u | 0x80000000u);
}
__device__ __forceinline__ float unsortable(unsigned k) {
    unsigned b = (k & 0x80000000u) ? (k & 0x7FFFFFFFu) : ~k;
    return __uint_as_float(b);
}

// ---------------- radix kth-value + band split ------------------------------------
// Above-band (certainly in top-k) -> tidx[row][0..na); in-band -> cand (rescored).
__global__ __launch_bounds__(256) void topk_band_kernel(const float* __restrict__ scores,
                                                        int* __restrict__ tidx,
                                                        int* __restrict__ cand,
                                                        int* __restrict__ cnt,
                                                        int* __restrict__ na_arr) {
    int row = blockIdx.x;
    int tid = threadIdx.x;
    __shared__ unsigned s_keys[DF];
    __shared__ int hist[256];
    __shared__ int sufs[256];
    __shared__ int s_misc[4];
    __shared__ int s_cnt, s_na;

    const float* sr = scores + (size_t)row * DF;
    for (int i = tid; i < DF; i += 256) s_keys[i] = sortable(sr[i]);
    if (tid == 0) { s_cnt = 0; s_na = 0; }

    unsigned prefix = 0;
    int krem = KSEL;
    for (int pass = 0; pass < 4; pass++) {
        int shift = 24 - pass * 8;
        unsigned hmask = (pass == 0) ? 0u : (0xFFFFFFFFu << (shift + 8));
        hist[tid] = 0;
        __syncthreads();
        for (int i = tid; i < DF; i += 256) {
            unsigned u = s_keys[i];
            if ((u & hmask) == prefix) atomicAdd(&hist[(u >> shift) & 0xFF], 1);
        }
        __syncthreads();
        sufs[tid] = hist[tid];
        __syncthreads();
#pragma unroll
        for (int off = 1; off < 256; off <<= 1) {
            int add = (tid + off < 256) ? sufs[tid + off] : 0;
            __syncthreads();
            sufs[tid] += add;
            __syncthreads();
        }
        if (sufs[tid] >= krem && (tid == 255 || sufs[tid + 1] < krem)) {
            s_misc[0] = tid;
            s_misc[1] = sufs[tid] - hist[tid];
        }
        __syncthreads();
        prefix |= ((unsigned)s_misc[0]) << shift;
        krem -= s_misc[1];
        __syncthreads();
    }
    float vf = unsortable(prefix);
    int* out = tidx + (size_t)row * KSEL;
    for (int i = tid; i < DF; i += 256) {
        float d = sr[i] - vf;
        if (d > BAND_DELTA) {
            int p = atomicAdd(&s_na, 1);
            out[p] = i;                       // guaranteed in final top-k
        } else if (d >= -BAND_DELTA) {
            int p = atomicAdd(&s_cnt, 1);
            if (p < CAP_ROW) cand[(size_t)row * CAP_ROW + p] = i;
        }
    }
    __syncthreads();
    if (tid == 0) {
        cnt[row] = s_cnt < CAP_ROW ? s_cnt : CAP_ROW;
        na_arr[row] = s_na;
    }
}

// ---------------- exact fp32 re-score of band candidates -> compact bscore --------
__global__ __launch_bounds__(256) void rescore_kernel(const float* __restrict__ h,
                                                      const float* __restrict__ Wr2,
                                                      const int* __restrict__ cand,
                                                      const int* __restrict__ cnt,
                                                      float* __restrict__ bscore) {
    int row = blockIdx.x;
    int lane = threadIdx.x & 63;
    int wv = threadIdx.x >> 6;
    int n = cnt[row];
    const float4* hp = (const float4*)(h + (size_t)row * DM);
    for (int c = wv; c < n; c += 4) {
        int col = cand[(size_t)row * CAP_ROW + c];
        const float4* wp = (const float4*)(Wr2 + (size_t)col * DM);
        float s = 0.f;
#pragma unroll
        for (int j = 0; j < 4; j++) {
            float4 a = hp[lane + 64 * j];
            float4 b = wp[lane + 64 * j];
            s = fmaf(a.x, b.x, s);
            s = fmaf(a.y, b.y, s);
            s = fmaf(a.z, b.z, s);
            s = fmaf(a.w, b.w, s);
        }
#pragma unroll
        for (int st = 1; st < 64; st <<= 1) s += __shfl_xor(s, st);
        if (lane == 0) bscore[(size_t)row * CAP_ROW + c] = s;
    }
}

// ---------------- band select: top (K-na) of band by (exact score, -idx) ----------
__global__ __launch_bounds__(256) void band_select_kernel(const float* __restrict__ bscore,
                                                          const int* __restrict__ cand,
                                                          const int* __restrict__ cnt,
                                                          const int* __restrict__ na_arr,
                                                          int* __restrict__ tidx) {
    int row = blockIdx.x;
    int tid = threadIdx.x;
    int n = cnt[row];
    int na = na_arr[row];
    int m = KSEL - na;
    __shared__ float ss[CAP_ROW];
    __shared__ int si[CAP_ROW];
    for (int i = tid; i < n; i += 256) {
        ss[i] = bscore[(size_t)row * CAP_ROW + i];
        si[i] = cand[(size_t)row * CAP_ROW + i];
    }
    __syncthreads();
    if (tid < n) {
        float s = ss[tid];
        int idx = si[tid];
        int rank = 0;
        for (int j = 0; j < n; j++) {
            float sj = ss[j];
            int ij = si[j];
            rank += (sj > s) || (sj == s && ij < idx);
        }
        if (rank < m) tidx[(size_t)row * KSEL + na + rank] = idx;
    }
}

// ---------------- DeepSets manifold: MFMA rho1 (round-11, unchanged) --------------
__global__ __launch_bounds__(256) void manifold_kernel(
    const float* __restrict__ z, const int* __restrict__ top_idx,
    const float* __restrict__ phi1_w, const float* __restrict__ phi1_b,
    const float* __restrict__ ln1w, const float* __restrict__ ln1b,
    const float* __restrict__ phi2_w, const float* __restrict__ phi2_b,
    const float* __restrict__ ln2w, const float* __restrict__ ln2b,
    const short* __restrict__ rho1b16, const float* __restrict__ rho1_b,
    const float* __restrict__ rho2_w, const float* __restrict__ rho2_b,
    float* __restrict__ man) {
    __shared__ __align__(16) short c_lds[256 * DH];
    __shared__ __align__(16) short w_lds[128 * DH];
    __shared__ float s_ctxp[4 * DH];
    __shared__ float s_ctx[DH];
    __shared__ float s_rho1b[2 * DH];
    __shared__ float s_rho2w[2 * DH];

    int tid = threadIdx.x;
    int t = blockIdx.x;
    int lane = tid & 63, wave = tid >> 6;
    int l16 = lane & 15, quad = lane >> 4;

    for (int b = tid; b < 128 * 8; b += 256) {
        int row = b >> 3, j = b & 7;
        *(short8*)(w_lds + row * DH + ((j ^ (row & 7)) * 8)) =
            *(const short8*)(rho1b16 + row * DH + j * 8);
    }
    if (tid < 2 * DH) { s_rho1b[tid] = rho1_b[tid]; s_rho2w[tid] = rho2_w[tid]; }

    int idx = top_idx[(size_t)t * KSEL + tid];
    float a = gelu_fast(z[(size_t)t * DF + idx]);
    f32x2 a2 = {a, a};

    f32x2 gv[DH2 / 2];
    f32x2 sv = {0.f, 0.f}, qv = {0.f, 0.f};
#pragma unroll
    for (int i = 0; i < DH2 / 2; i++) {
        f32x2 w = ((const f32x2*)phi1_w)[i];
        f32x2 b = ((const f32x2*)phi1_b)[i];
        f32x2 e = pkfma(a2, w, b);
        gv[i] = e;
        sv = sv + e;
        qv = pkfma(e, e, qv);
    }
    float s = sv.x + sv.y, s2 = qv.x + qv.y;
    float mu = s * (1.0f / DH2);
    float rs = rsqrtf(s2 * (1.0f / DH2) - mu * mu + 1e-5f);
    f32x2 muv = {mu, mu}, rsv = {rs, rs};
#pragma unroll
    for (int i = 0; i < DH2 / 2; i++) {
        f32x2 t2 = (gv[i] - muv) * rsv;
        t2 = pkfma(t2, ((const f32x2*)ln1w)[i], ((const f32x2*)ln1b)[i]);
        gv[i] = (f32x2){gelu_fast(t2.x), gelu_fast(t2.y)};
    }

    f32x2 hv[DH / 2];
#pragma unroll
    for (int j2 = 0; j2 < DH / 2; j2++) {
        const f32x2* wa = (const f32x2*)(phi2_w + (2 * j2) * DH2);
        const f32x2* wb = (const f32x2*)(phi2_w + (2 * j2 + 1) * DH2);
        f32x2 ra = {phi2_b[2 * j2], 0.f};
        f32x2 rb = {phi2_b[2 * j2 + 1], 0.f};
#pragma unroll
        for (int i = 0; i < DH2 / 2; i++) {
            ra = pkfma(gv[i], wa[i], ra);
            rb = pkfma(gv[i], wb[i], rb);
        }
        hv[j2] = (f32x2){ra.x + ra.y, rb.x + rb.y};
    }

    f32x2 tsv = {0.f, 0.f}, tqv = {0.f, 0.f};
#pragma unroll
    for (int j2 = 0; j2 < DH / 2; j2++) {
        tsv = tsv + hv[j2];
        tqv = pkfma(hv[j2], hv[j2], tqv);
    }
    float tsum = tsv.x + tsv.y, tsq = tqv.x + tqv.y;
    float mu2 = tsum * (1.0f / DH);
    float rs2 = rsqrtf(tsq * (1.0f / DH) - mu2 * mu2 + 1e-5f);
    f32x2 mu2v = {mu2, mu2}, rs2v = {rs2, rs2};
#pragma unroll
    for (int j2 = 0; j2 < DH / 2; j2++) {
        f32x2 t2 = (hv[j2] - mu2v) * rs2v;
        hv[j2] = pkfma(t2, ((const f32x2*)ln2w)[j2], ((const f32x2*)ln2b)[j2]);
    }

#pragma unroll
    for (int j2 = 0; j2 < DH / 2; j2++) {
        float vx = hv[j2].x, vy = hv[j2].y;
#pragma unroll
        for (int st = 1; st < 64; st <<= 1) {
            vx += __shfl_xor(vx, st);
            vy += __shfl_xor(vy, st);
        }
        if (lane == 0) {
            s_ctxp[wave * DH + 2 * j2] = vx;
            s_ctxp[wave * DH + 2 * j2 + 1] = vy;
        }
    }
    __syncthreads();
    if (tid < DH)
        s_ctx[tid] = (s_ctxp[tid] + s_ctxp[DH + tid] + s_ctxp[2 * DH + tid] +
                      s_ctxp[3 * DH + tid]) * (1.0f / KSEL);
    __syncthreads();

#pragma unroll
    for (int j = 0; j < 8; j++) {
        short8 pk;
#pragma unroll
        for (int i2 = 0; i2 < 4; i2++) {
            f32x2 v = hv[4 * j + i2] + ((const f32x2*)s_ctx)[4 * j + i2];
            pk[2 * i2] = (short)bf16_rne(v.x);
            pk[2 * i2 + 1] = (short)bf16_rne(v.y);
        }
        *(short8*)(c_lds + tid * DH + ((j ^ (tid & 7)) * 8)) = pk;
    }
    __syncthreads();

    int wbase = wave * 64;
    short8 af[4][2];
#pragma unroll
    for (int tm = 0; tm < 4; tm++)
#pragma unroll
        for (int kf = 0; kf < 2; kf++) {
            int m = wbase + tm * 16 + l16;
            int cl = (kf * 4 + quad) ^ (m & 7);
            af[tm][kf] = *(const short8*)(c_lds + m * DH + cl * 8);
        }
    float mpart[4][4] = {};
#pragma unroll
    for (int tn = 0; tn < 8; tn++) {
        int n = tn * 16 + l16;
        short8 bf[2];
#pragma unroll
        for (int kf = 0; kf < 2; kf++) {
            int cl = (kf * 4 + quad) ^ (n & 7);
            bf[kf] = *(const short8*)(w_lds + n * DH + cl * 8);
        }
        f32x4 acc[4] = {};
#pragma unroll
        for (int kf = 0; kf < 2; kf++)
#pragma unroll
            for (int tm = 0; tm < 4; tm++)
                acc[tm] = __builtin_amdgcn_mfma_f32_16x16x32_bf16(
                    af[tm][kf], bf[kf], acc[tm], 0, 0, 0);
        float b1 = s_rho1b[n];
        float w2v = s_rho2w[n];
#pragma unroll
        for (int tm = 0; tm < 4; tm++)
#pragma unroll
            for (int r = 0; r < 4; r++)
                mpart[tm][r] = fmaf(gelu_fast(acc[tm][r] + b1), w2v, mpart[tm][r]);
    }
#pragma unroll
    for (int tm = 0; tm < 4; tm++)
#pragma unroll
        for (int r = 0; r < 4; r++) {
            float v = mpart[tm][r];
            v += __shfl_xor(v, 1);
            v += __shfl_xor(v, 2);
            v += __shfl_xor(v, 4);
            v += __shfl_xor(v, 8);
            mpart[tm][r] = v;
        }
    if (l16 == 0) {
        float b2 = rho2_b[0];
#pragma unroll
        for (int tm = 0; tm < 4; tm++)
#pragma unroll
            for (int r = 0; r < 4; r++)
                man[(size_t)t * KSEL + wbase + tm * 16 + quad * 4 + r] =
                    mpart[tm][r] + b2;
    }
}

// ---------------- scatter man (as fp16) into zeroed fp16 a_man --------------------
__global__ __launch_bounds__(256) void scatter_f16_kernel(const float* __restrict__ man,
                                                          const int* __restrict__ top_idx,
                                                          short* __restrict__ a_man) {
    int t = blockIdx.x, k = threadIdx.x;
    a_man[(size_t)t * DF + top_idx[(size_t)t * KSEL + k]] =
        __builtin_bit_cast(short, (_Float16)man[(size_t)t * KSEL + k]);
}

extern "C" void kernel_launch(void* const* d_in, const int* in_sizes, int n_in,
                              void* d_out, int out_size, void* d_ws, size_t ws_size,
                              hipStream_t stream) {
    const float* x      = (const float*)d_in[0];
    const float* W1     = (const float*)d_in[1];
    const float* W2     = (const float*)d_in[2];
    const float* Wr1    = (const float*)d_in[3];
    const float* Wr2    = (const float*)d_in[4];
    const float* ln_w   = (const float*)d_in[5];
    const float* ln_b   = (const float*)d_in[6];
    const float* phi1_w = (const float*)d_in[7];
    const float* phi1_b = (const float*)d_in[8];
    const float* pl1w   = (const float*)d_in[9];
    const float* pl1b   = (const float*)d_in[10];
    const float* phi2_w = (const float*)d_in[11];
    const float* phi2_b = (const float*)d_in[12];
    const float* pl2w   = (const float*)d_in[13];
    const float* pl2b   = (const float*)d_in[14];
    const float* rho1_w = (const float*)d_in[15];
    const float* rho1_b = (const float*)d_in[16];
    const float* rho2_w = (const float*)d_in[17];
    const float* rho2_b = (const float*)d_in[18];
    float* out = (float*)d_out;

    char* ws = (char*)d_ws;
    size_t off = 0;
    auto alloc = [&](size_t bytes) {
        char* p = ws + off;
        off += (bytes + 255) & ~(size_t)255;
        return p;
    };
    float* xn     = (float*)alloc(sizeof(float) * (size_t)T_TOKENS * DM);   // 16 MB
    float* h      = (float*)alloc(sizeof(float) * (size_t)T_TOKENS * DM);   // 16 MB
    float* scores = (float*)alloc(sizeof(float) * (size_t)T_TOKENS * DF);   // 64 MB
    float* z      = (float*)alloc(sizeof(float) * (size_t)T_TOKENS * DF);   // 64 MB
    int*   tidx   = (int*)alloc(sizeof(int) * (size_t)T_TOKENS * KSEL);     // 4 MB
    float* man    = (float*)alloc(sizeof(float) * (size_t)T_TOKENS * KSEL); // 4 MB
    int*   cand   = (int*)alloc(sizeof(int) * (size_t)T_TOKENS * CAP_ROW);  // 4 MB
    float* bscore = (float*)alloc(sizeof(float) * (size_t)T_TOKENS * CAP_ROW); // 4 MB
    int*   cnt    = (int*)alloc(sizeof(int) * (size_t)T_TOKENS);
    int*   na_arr = (int*)alloc(sizeof(int) * (size_t)T_TOKENS);
    short* rho1b16 = (short*)alloc(sizeof(short) * 2 * DH * DH);

    // Region reuse (stream-serial, lifetimes disjoint):
    short* h_hi   = (short*)z;                          // 8 MB (z written at step 8)
    short* wr2_hi = (short*)z + (size_t)T_TOKENS * DM;  // next 8 MB of z
    short* xf16   = (short*)xn;      // 8 MB, after router GEMM1
    short* w1f16  = (short*)h;       // 8 MB, after rescore
    short* amanb  = (short*)scores;  // 16 MB fp16, after topk_band
    short* w2f16  = (short*)z;       // 8 MB, after manifold

    // 1. x_norm = LN(x)
    ln_kernel<<<T_TOKENS, 256, 0, stream>>>(x, ln_w, ln_b, xn);
    // 2. h = gelu(xn @ Wr1^T)   (fp32 exact — h feeds exact rescoring)
    gemm_f32_128<<<dim3(DM / 128, T_TOKENS / 128), 256, 0, stream>>>(xn, Wr1, h, T_TOKENS, DM, DM, 1);
    // 3. approx scores = h_hi @ Wr2_hi^T  (bf16 MFMA)
    cvt_bf16_kernel<<<(T_TOKENS * DM / 4 + 255) / 256, 256, 0, stream>>>(h, h_hi, T_TOKENS * DM / 4);
    cvt_bf16_kernel<<<(DF * DM / 4 + 255) / 256, 256, 0, stream>>>(Wr2, wr2_hi, DF * DM / 4);
    gemm_bf16<<<dim3(DF / 128, T_TOKENS / 128), 256, 0, stream>>>(
        h_hi, wr2_hi, scores, T_TOKENS, DF, DM, DM, DM, 0);
    // 4. band split: above-band -> tidx directly; in-band -> cand
    topk_band_kernel<<<T_TOKENS, 256, 0, stream>>>(scores, tidx, cand, cnt, na_arr);
    // 5. exact fp32 re-score of band; rank-select fills tidx[na..256)
    rescore_kernel<<<T_TOKENS, 256, 0, stream>>>(h, Wr2, cand, cnt, bscore);
    band_select_kernel<<<T_TOKENS, 256, 0, stream>>>(bscore, cand, cnt, na_arr, tidx);
    // 6. fp16 conversions
    cvt_f16_kernel<<<(T_TOKENS * DM / 4 + 255) / 256, 256, 0, stream>>>(x, xf16, T_TOKENS * DM / 4);
    cvt_f16_kernel<<<(DF * DM / 4 + 255) / 256, 256, 0, stream>>>(W1, w1f16, DF * DM / 4);
    cvt_bf16_kernel<<<(2 * DH * DH / 4 + 255) / 256, 256, 0, stream>>>(rho1_w, rho1b16, 2 * DH * DH / 4);
    // 7. z = x @ W1^T  (single-pass fp16 MFMA; z feeds only LN-suppressed manifold)
    gemm_f16<<<dim3(DF / 128, T_TOKENS / 128), 256, 0, stream>>>(
        xf16, w1f16, z, T_TOKENS, DF, DM, DM, DM);
    // 8. manifold (MFMA rho1)
    manifold_kernel<<<T_TOKENS, 256, 0, stream>>>(z, tidx, phi1_w, phi1_b, pl1w, pl1b,
                                                  phi2_w, phi2_b, pl2w, pl2b,
                                                  rho1b16, rho1_b, rho2_w, rho2_b, man);
    // 9. scatter man -> fp16 a_man; W2 -> fp16
    hipMemsetAsync(amanb, 0, sizeof(short) * (size_t)T_TOKENS * DF, stream);
    scatter_f16_kernel<<<T_TOKENS, 256, 0, stream>>>(man, tidx, amanb);
    cvt_f16_kernel<<<(DM * DF / 4 + 255) / 256, 256, 0, stream>>>(W2, w2f16, DM * DF / 4);
    // 10. out = a_man @ W2^T  (fp16 MFMA)
    gemm_f16<<<dim3(DM / 128, T_TOKENS / 128), 256, 0, stream>>>(
        amanb, w2f16, out, T_TOKENS, DM, DF, DF, DF);
}